// Round 17
// baseline (451.726 us; speedup 1.0000x reference)
//
#include <hip/hip_runtime.h>
#include <hip/hip_bf16.h>
#include <math.h>

#define NN 20000
#define NE 320000
#define NG 128
#define DD 64
#define FA 92
#define FF 128
#define NT (NE / 16)          // 16-edge MFMA tiles = 20000
#define NBLK 2500             // edge_pre3 blocks (8 tiles/block, 1/wave, both gates)
#define NAB 1250              // apply_node blocks (16 threads/node)
#define NHB 625               // h_update blocks (NN*DD/8/256)
#define GAMMA 3.875f          // 31/8
#define CEN (8.0f / 31.0f)    // center spacing
#define L2E 1.44269504f
#define RBF2 (-GAMMA * L2E)   // exp(-g u^2) = exp2(u^2 * RBF2)

typedef __attribute__((ext_vector_type(8))) short bf16x8;
typedef __attribute__((ext_vector_type(4))) float f32x4;

// stats layout (floats): [0..127]=q(I|U), [256..383]=zsumS/zsumD, [384..415]=zsumR

__device__ __forceinline__ float sp_(float x) {
    return fmaxf(x, 0.f) + __logf(1.f + __expf(-fabsf(x)));
}
__device__ __forceinline__ unsigned short f2b(float x) {
    __hip_bfloat16 b = __float2bfloat16(x);
    return *reinterpret_cast<unsigned short*>(&b);
}
__device__ __forceinline__ float b2f(unsigned short u) {
    return __uint_as_float((unsigned)u << 16);
}

// halving tree: lane r (within 16-lane group) returns sum over group of v_orig[.][r]
__device__ __forceinline__ float tree16(float v[16], int r) {
#pragma unroll
    for (int m = 1; m < 16; m <<= 1) {
        bool b = (r & m) != 0;
        int cnt = 8 / m;   // outputs this step: 8,4,2,1
#pragma unroll
        for (int i = 0; i < cnt; ++i) {
            float keep = b ? v[2 * i + 1] : v[2 * i];
            float disc = b ? v[2 * i] : v[2 * i + 1];
            float recv = __shfl_xor(disc, m, 64);
            v[i] = keep + recv;
        }
    }
    return v[0];
}

// ---------------- embedding (blocks 0..624) + weight fragment prep (blocks 625..630) ----------------
__global__ __launch_bounds__(256) void embed_k(const float* __restrict__ af,
                                               const float* __restrict__ W,
                                               const float* __restrict__ b,
                                               float* __restrict__ h,
                                               unsigned short* __restrict__ hb,
                                               const float* __restrict__ Wi,
                                               const float* __restrict__ Wu,
                                               unsigned short* __restrict__ Wf) {
    if (blockIdx.x >= NN / 32) {
        int bb = blockIdx.x - NN / 32;   // 0..5 : layer*2 + gate
        int l = bb >> 1, g = bb & 1;
        const float* Wsrc = (g ? Wu : Wi) + (size_t)l * 160 * DD;
        for (int f = threadIdx.x; f < 10240; f += 256) {
            int i = f & 7;
            int lane = (f >> 3) & 63;
            int nf = (f >> 9) & 3;
            int kt = f >> 11;
            int k = kt * 32 + 8 * (lane >> 4) + i;
            int col = nf * 16 + (lane & 15);
            Wf[(size_t)bb * 10240 + f] = f2b(Wsrc[k * DD + col]);
        }
        return;
    }
    __shared__ float Ws[FA * DD];   // 23552 B
    __shared__ float afS[32][FA];   // 11776 B
    const int n0 = blockIdx.x * 32;
    for (int i = threadIdx.x * 4; i < FA * DD; i += 256 * 4)
        *(float4*)&Ws[i] = *(const float4*)&W[i];
    const float4* af4 = (const float4*)(af + (size_t)n0 * FA);
    for (int i = threadIdx.x; i < 32 * FA / 4; i += 256) {
        float4 v = af4[i];
        int nl = i / (FA / 4), kk = (i % (FA / 4)) * 4;
        *(float4*)&afS[nl][kk] = v;
    }
    __syncthreads();
    int nl = threadIdx.x >> 3, ch = threadIdx.x & 7;
    int n = n0 + nl;
    float acc[8];
#pragma unroll
    for (int q = 0; q < 8; ++q) acc[q] = b[ch * 8 + q];
#pragma unroll 4
    for (int k = 0; k < FA; ++k) {
        float a = afS[nl][k];
        const float* wr = &Ws[k * DD + ch * 8];
        float4 w0 = *(const float4*)wr;
        float4 w1 = *(const float4*)(wr + 4);
        acc[0] += a * w0.x; acc[1] += a * w0.y; acc[2] += a * w0.z; acc[3] += a * w0.w;
        acc[4] += a * w1.x; acc[5] += a * w1.y; acc[6] += a * w1.z; acc[7] += a * w1.w;
    }
    float* o = h + (size_t)n * DD + ch * 8;
    float4 o0, o1;
    o0.x = acc[0]; o0.y = acc[1]; o0.z = acc[2]; o0.w = acc[3];
    o1.x = acc[4]; o1.y = acc[5]; o1.z = acc[6]; o1.w = acc[7];
    *(float4*)o = o0;
    *(float4*)(o + 4) = o1;
    bf16x8 hb8;
#pragma unroll
    for (int q = 0; q < 8; ++q) hb8[q] = (short)f2b(acc[q]);
    *(bf16x8*)(hb + (size_t)n * DD + ch * 8) = hb8;
}

// ---------------- CSR build (sorted-by-dst edge order) ----------------
__global__ void cnt_edges_k(const int* __restrict__ src, const int* __restrict__ dst,
                            int* __restrict__ icnt, int* __restrict__ ocnt) {
    int e = blockIdx.x * 256 + threadIdx.x;
    if (e < NE) {
        atomicAdd(&icnt[dst[e]], 1);
        atomicAdd(&ocnt[src[e]], 1);
    }
}

__global__ __launch_bounds__(1024) void csr_scan_k(const int* __restrict__ cnt,
                                                   int* __restrict__ off,
                                                   int* __restrict__ cur) {
    __shared__ int part[1024];
    int t = threadIdx.x;
    int base = t * 20;
    int s = 0;
    for (int i = 0; i < 20; ++i) { int idx = base + i; if (idx < NN) s += cnt[idx]; }
    part[t] = s;
    __syncthreads();
    for (int ofs = 1; ofs < 1024; ofs <<= 1) {
        int v = (t >= ofs) ? part[t - ofs] : 0;
        __syncthreads();
        part[t] += v;
        __syncthreads();
    }
    int run = (t == 0) ? 0 : part[t - 1];
    for (int i = 0; i < 20; ++i) {
        int idx = base + i;
        if (idx < NN) { off[idx] = run; cur[idx] = run; run += cnt[idx]; }
    }
    if (t == 1023) off[NN] = run;
}

__global__ void fill_edges_k(const int* __restrict__ src, const int* __restrict__ dst,
                             const float* __restrict__ bond,
                             int* __restrict__ cur, int* __restrict__ ssrc,
                             int* __restrict__ sdst, float* __restrict__ bond_s) {
    int e = blockIdx.x * 256 + threadIdx.x;
    if (e < NE) {
        int d = dst[e];
        int p = atomicAdd(&cur[d], 1);
        ssrc[p] = src[e];
        sdst[p] = d;
        bond_s[p] = bond[e];
    }
}

// ---------------- fused one-time stats: rbf col-sums (blocks <512) + zsum (blocks >=512) ----------------
__global__ __launch_bounds__(256) void rbfzsum_k(const float* __restrict__ bond,
                                                 const unsigned short* __restrict__ hb,
                                                 const int* __restrict__ ocnt,
                                                 const int* __restrict__ icnt,
                                                 float* __restrict__ zr,
                                                 float* __restrict__ zS,
                                                 float* __restrict__ zD) {
    if (blockIdx.x < 512) {
        __shared__ float part[4][32];
        int lane = threadIdx.x & 63;
        int w = threadIdx.x >> 6;
        int col = lane & 31;
        int half = lane >> 5;
        int slot = (blockIdx.x * 4 + w) * 2 + half;
        int nslots = 512 * 8;
        float cen = (float)col * CEN;
        float a = 0.f;
        for (int e = slot; e < NE; e += nslots) {
            float u = bond[e] - cen;
            a += b2f(f2b(__builtin_amdgcn_exp2f(u * u * RBF2)));
        }
        a += __shfl_xor(a, 32, 64);
        if (half == 0) part[w][col] = a;
        __syncthreads();
        if (threadIdx.x < 32) {
            float s = part[0][threadIdx.x] + part[1][threadIdx.x] +
                      part[2][threadIdx.x] + part[3][threadIdx.x];
            unsafeAtomicAdd(&zr[threadIdx.x], s);
        }
    } else {
        int bb = blockIdx.x - 512;  // 0..127
        int t = bb * 256 + threadIdx.x;
        int col = t & 63;
        int n0 = t >> 6;
        int nstride = (128 * 256) >> 6;
        float aS = 0.f, aD = 0.f;
        for (int n = n0; n < NN; n += nstride) {
            float v = b2f(hb[(size_t)n * DD + col]);
            aS += (float)ocnt[n] * v;
            aD += (float)icnt[n] * v;
        }
        unsafeAtomicAdd(&zS[col], aS);
        unsafeAtomicAdd(&zD[col], aD);
    }
}

// ---------------- gather-GEMM, BOTH gates, 512 thr, 40KB LDS, coalesced stores via LDS repack ----------------
__global__ __launch_bounds__(512, 8) void edge_pre3_k(const unsigned short* __restrict__ hb,
                                                      const float* __restrict__ bond_s,
                                                      const unsigned short* __restrict__ Wf, // layer base [2][10240]
                                                      const int* __restrict__ ssrc,
                                                      const int* __restrict__ sdst,
                                                      unsigned short* __restrict__ preIb,
                                                      unsigned short* __restrict__ preUb,
                                                      float* __restrict__ pq) {
    __shared__ bf16x8 WfS[2560];      // 40960 B : both gates; gate-I region reused as repack slots + qred
    unsigned short* tbuf = (unsigned short*)WfS;  // repack slots: wave w at ushort offset w*1152 (16 rows x 72)
    float* qred = (float*)WfS;
    const int bidx = blockIdx.x;      // 0..NBLK-1
    const int lane = threadIdx.x & 63;
    const int w = threadIdx.x >> 6;   // 0..7
    const int r = lane & 15;          // edge-within-tile
    const int c = lane >> 4;          // k-chunk
    const int tile = bidx * 8 + w;    // exactly NT tiles
    const int e = tile * 16 + r;

    int es = ssrc[e];
    int ed = sdst[e];
    float bd = bond_s[e];
    bf16x8 a0 = *(const bf16x8*)(hb + (size_t)es * DD + c * 8);
    bf16x8 a1 = *(const bf16x8*)(hb + (size_t)es * DD + 32 + c * 8);
    bf16x8 a2 = *(const bf16x8*)(hb + (size_t)ed * DD + c * 8);
    bf16x8 a3 = *(const bf16x8*)(hb + (size_t)ed * DD + 32 + c * 8);
    bf16x8 a4;
#pragma unroll
    for (int i = 0; i < 8; ++i) {
        float u = bd - (float)(8 * c + i) * CEN;
        a4[i] = (short)f2b(__builtin_amdgcn_exp2f(u * u * RBF2));
    }

    {
        const bf16x8* Wf8 = (const bf16x8*)Wf;
        for (int i = threadIdx.x; i < 2560; i += 512) WfS[i] = Wf8[i];
    }
    __syncthreads();

    float qI[16], qU[16];
    // gate I
    f32x4 accI[4];
    {
#pragma unroll
        for (int nf = 0; nf < 4; ++nf) { f32x4 z4 = {0.f, 0.f, 0.f, 0.f}; accI[nf] = z4; }
#pragma unroll
        for (int kt = 0; kt < 5; ++kt) {
            bf16x8 a = (kt == 0) ? a0 : (kt == 1) ? a1 : (kt == 2) ? a2 : (kt == 3) ? a3 : a4;
#pragma unroll
            for (int nf = 0; nf < 4; ++nf)
                accI[nf] = __builtin_amdgcn_mfma_f32_16x16x32_bf16(WfS[(kt * 4 + nf) * 64 + lane], a, accI[nf], 0, 0, 0);
        }
#pragma unroll
        for (int nf = 0; nf < 4; ++nf)
#pragma unroll
            for (int j = 0; j < 4; ++j) qI[nf * 4 + j] = accI[nf][j] * accI[nf][j];
    }
    __syncthreads();   // all waves done with gate-I weights -> slots usable

    unsigned short* slot = tbuf + w * 1152;   // 16 rows x 72 ushorts (144 B, 16B-aligned)
    // repack + coalesced store, gate I
    {
#pragma unroll
        for (int nf = 0; nf < 4; ++nf) {
            ushort4 o;
            o.x = f2b(accI[nf][0]); o.y = f2b(accI[nf][1]);
            o.z = f2b(accI[nf][2]); o.w = f2b(accI[nf][3]);
            *(ushort4*)(slot + r * 72 + c * 4 + nf * 16) = o;
        }
        bf16x8 v0 = *(const bf16x8*)(slot + (lane >> 2) * 72 + (lane & 3) * 16);
        bf16x8 v1 = *(const bf16x8*)(slot + (lane >> 2) * 72 + (lane & 3) * 16 + 8);
        unsigned short* dst0 = preIb + (size_t)tile * 1024 + lane * 16;
        *(bf16x8*)dst0 = v0;
        *(bf16x8*)(dst0 + 8) = v1;
    }
    // gate U (reuses a0..a4 in registers; gate-U weights untouched at WfS[1280..])
    {
        f32x4 acc[4];
#pragma unroll
        for (int nf = 0; nf < 4; ++nf) { f32x4 z4 = {0.f, 0.f, 0.f, 0.f}; acc[nf] = z4; }
#pragma unroll
        for (int kt = 0; kt < 5; ++kt) {
            bf16x8 a = (kt == 0) ? a0 : (kt == 1) ? a1 : (kt == 2) ? a2 : (kt == 3) ? a3 : a4;
#pragma unroll
            for (int nf = 0; nf < 4; ++nf)
                acc[nf] = __builtin_amdgcn_mfma_f32_16x16x32_bf16(WfS[1280 + (kt * 4 + nf) * 64 + lane], a, acc[nf], 0, 0, 0);
        }
#pragma unroll
        for (int nf = 0; nf < 4; ++nf) {
            ushort4 o;
            o.x = f2b(acc[nf][0]); o.y = f2b(acc[nf][1]);
            o.z = f2b(acc[nf][2]); o.w = f2b(acc[nf][3]);
            *(ushort4*)(slot + r * 72 + c * 4 + nf * 16) = o;
#pragma unroll
            for (int j = 0; j < 4; ++j) qU[nf * 4 + j] = acc[nf][j] * acc[nf][j];
        }
        bf16x8 v0 = *(const bf16x8*)(slot + (lane >> 2) * 72 + (lane & 3) * 16);
        bf16x8 v1 = *(const bf16x8*)(slot + (lane >> 2) * 72 + (lane & 3) * 16 + 8);
        unsigned short* dst0 = preUb + (size_t)tile * 1024 + lane * 16;
        *(bf16x8*)dst0 = v0;
        *(bf16x8*)(dst0 + 8) = v1;
    }

    // sumsq reduce across the 16 r-lanes (halving tree); then cross-wave via aliased LDS
    float vI = tree16(qI, r);
    float vU = tree16(qU, r);
    int col = (r >> 2) * 16 + c * 4 + (r & 3);
    __syncthreads();   // all waves done with their slots -> qred region safe
    qred[w * 128 + col] = vI;
    qred[w * 128 + 64 + col] = vU;
    __syncthreads();
    if (threadIdx.x < 128) {
        float s8 = 0.f;
#pragma unroll
        for (int ww = 0; ww < 8; ++ww) s8 += qred[ww * 128 + threadIdx.x];
        pq[(size_t)threadIdx.x * NBLK + bidx] = s8;  // rows: 0..63 = qI, 64..127 = qU
    }
}

// ---------------- fused reduce + last-block BN coeffs (gate/update) ----------------
// blocks 0..127: pq rows -> stats[0..127]; blocks 128..255 (withz): zpart rows -> stats[256..383]
// last arriving block computes coeff (fin_iu) with log2e folded.
__global__ __launch_bounds__(256) void red2f_k(const float* __restrict__ pq,
                                               const float* __restrict__ zpart,
                                               float* __restrict__ stats, int withz,
                                               int* __restrict__ counter,
                                               const unsigned short* __restrict__ Wf,
                                               const float* __restrict__ gi, const float* __restrict__ bbi,
                                               const float* __restrict__ gu, const float* __restrict__ bbu,
                                               float* __restrict__ coeff) {
    __shared__ float red[256];
    __shared__ int isLast;
    int b = blockIdx.x;
    if (b < 128 || withz) {
        const float* row;
        float* out;
        int len;
        if (b < 128) { row = pq + (size_t)b * NBLK; out = &stats[b]; len = NBLK; }
        else { row = zpart + (size_t)(b - 128) * NHB; out = &stats[256 + (b - 128)]; len = NHB; }
        float s = 0.f;
        for (int i = threadIdx.x; i < len; i += 256) s += row[i];
        red[threadIdx.x] = s;
        __syncthreads();
        for (int ofs = 128; ofs >= 1; ofs >>= 1) {
            if (threadIdx.x < ofs) red[threadIdx.x] += red[threadIdx.x + ofs];
            __syncthreads();
        }
        if (threadIdx.x == 0) *out = red[0];
    }
    __threadfence();
    if (threadIdx.x == 0) {
        int old = atomicAdd(counter, 1);
        isLast = (old == gridDim.x - 1);
        if (isLast) atomicExch(counter, 0);  // reset for next launch/replay
    }
    __syncthreads();
    if (!isLast) return;
    __threadfence();

    // fin_iu body (256 threads: 4-way k split + LDS reduce)
    volatile const float* vstats = stats;
    __shared__ float redI[256], redU[256];
    int t = threadIdx.x;
    int j = t & 63, part = t >> 6;
    int nf = j >> 4, rr = j & 15;
    float muI = 0.f, muU = 0.f;
    for (int k = part; k < 160; k += 4) {
        float zs = (k < 128) ? vstats[256 + k] : vstats[384 + k - 128];
        int kt = k >> 5, rem = k & 31, cc = rem >> 3, ii = rem & 7;
        int f = kt * 2048 + nf * 512 + (cc * 16 + rr) * 8 + ii;
        muI += zs * b2f(Wf[f]);
        muU += zs * b2f(Wf[10240 + f]);
    }
    redI[t] = muI;
    redU[t] = muU;
    __syncthreads();
    if (t < 64) {
        muI = redI[t] + redI[64 + t] + redI[128 + t] + redI[192 + t];
        muU = redU[t] + redU[64 + t] + redU[128 + t] + redU[192 + t];
        const float invE = 1.f / (float)NE;
        muI *= invE; muU *= invE;
        float varI = vstats[t] * invE - muI * muI;
        float sI = gi[t] * rsqrtf(varI + 1e-5f);
        float tI = bbi[t] - muI * sI;
        float varU = vstats[64 + t] * invE - muU * muU;
        float sU = gu[t] * rsqrtf(varU + 1e-5f);
        float tU = bbu[t] - muU * sU;
        coeff[t]       = -L2E * sI;
        coeff[64 + t]  = -L2E * tI;
        coeff[128 + t] =  L2E * sU;
        coeff[192 + t] =  L2E * tU;
    }
}

// ---------------- node-parallel apply (16 thr/node, x8 loads) + fused m stats ----------------
// act = log(1+2^xu') * rcp(1+2^xi')  — global ln2 factor dropped (BN scale-invariant)
__global__ __launch_bounds__(256) void apply_node_k(const unsigned short* __restrict__ preIb,
                                                    const unsigned short* __restrict__ preUb,
                                                    const int* __restrict__ eoff,
                                                    const float* __restrict__ coeff,
                                                    float* __restrict__ m,
                                                    float* __restrict__ mpart) {
    __shared__ float ps[128][8];
    __shared__ float pq2[128][8];
    int ch = threadIdx.x & 7;
    int half = (threadIdx.x >> 3) & 1;
    int nl = threadIdx.x >> 4;              // 0..15
    int n = blockIdx.x * 16 + nl;
    float sIv[8], tIv[8], sUv[8], tUv[8];
#pragma unroll
    for (int q = 0; q < 8; ++q) {
        int col = ch * 8 + q;
        sIv[q] = coeff[col];       tIv[q] = coeff[64 + col];
        sUv[q] = coeff[128 + col]; tUv[q] = coeff[192 + col];
    }
    int b = eoff[n], e = eoff[n + 1];
    float acc[8];
#pragma unroll
    for (int q = 0; q < 8; ++q) acc[q] = 0.f;
    for (int p = b + half; p < e; p += 2) {
        bf16x8 vi = *(const bf16x8*)(preIb + (size_t)p * DD + ch * 8);
        bf16x8 vu = *(const bf16x8*)(preUb + (size_t)p * DD + ch * 8);
#pragma unroll
        for (int q = 0; q < 8; ++q) {
            float xi = fmaf(b2f((unsigned short)vi[q]), sIv[q], tIv[q]);
            float den = 1.f + __builtin_amdgcn_exp2f(xi);
            float xu = fmaf(b2f((unsigned short)vu[q]), sUv[q], tUv[q]);
            float lu = __builtin_amdgcn_logf(1.f + __builtin_amdgcn_exp2f(xu));
            acc[q] = fmaf(lu, __builtin_amdgcn_rcpf(den), acc[q]);
        }
    }
#pragma unroll
    for (int q = 0; q < 8; ++q) acc[q] += __shfl_xor(acc[q], 8, 64);
    if (half == 0) {
        float* mp = m + (size_t)n * DD + ch * 8;
        float4 v0, v1;
        v0.x = acc[0]; v0.y = acc[1]; v0.z = acc[2]; v0.w = acc[3];
        v1.x = acc[4]; v1.y = acc[5]; v1.z = acc[6]; v1.w = acc[7];
        *(float4*)mp = v0;
        *(float4*)(mp + 4) = v1;
        int idx = nl * 8 + ch;  // 0..127
#pragma unroll
        for (int q = 0; q < 8; ++q) {
            ps[idx][q] = acc[q];
            pq2[idx][q] = acc[q] * acc[q];
        }
    }
    __syncthreads();
    if (threadIdx.x < 64) {
        int j = threadIdx.x;
        int chh = j >> 3, qq = j & 7;
        float s = 0.f, q2 = 0.f;
#pragma unroll
        for (int nn = 0; nn < 16; ++nn) {
            s += ps[nn * 8 + chh][qq];
            q2 += pq2[nn * 8 + chh][qq];
        }
        mpart[(size_t)j * NAB + blockIdx.x] = s;
        mpart[(size_t)(64 + j) * NAB + blockIdx.x] = q2;
    }
}

// ---------------- fused mpart reduce + BN(m) coeffs: 64 blocks, block j -> col j ----------------
__global__ __launch_bounds__(256) void fin_n3_k(const float* __restrict__ mpart,
                                                const float* __restrict__ gn,
                                                const float* __restrict__ bbn,
                                                float* __restrict__ coeffN) {
    __shared__ float red1[256], red2[256];
    int j = blockIdx.x; // 0..63
    float s1 = 0.f, s2 = 0.f;
    for (int i = threadIdx.x; i < NAB; i += 256) {
        s1 += mpart[(size_t)j * NAB + i];
        s2 += mpart[(size_t)(64 + j) * NAB + i];
    }
    red1[threadIdx.x] = s1;
    red2[threadIdx.x] = s2;
    __syncthreads();
    for (int ofs = 128; ofs >= 1; ofs >>= 1) {
        if (threadIdx.x < ofs) {
            red1[threadIdx.x] += red1[threadIdx.x + ofs];
            red2[threadIdx.x] += red2[threadIdx.x + ofs];
        }
        __syncthreads();
    }
    if (threadIdx.x == 0) {
        const float invN = 1.f / (float)NN;
        float mu = red1[0] * invN;
        float var = red2[0] * invN - mu * mu;
        float sc = gn[j] * rsqrtf(var + 1e-5f);
        coeffN[j] = sc;
        coeffN[64 + j] = bbn[j] - mu * sc;
    }
}

// ---------------- h = sp(h + bn(m)), 8-wide; non-fin fuses next-layer zsum partials ----------------
__global__ __launch_bounds__(256) void h_update_k(float* __restrict__ h,
                                                  unsigned short* __restrict__ hb,
                                                  const float* __restrict__ m,
                                                  const float* __restrict__ coeffN,
                                                  const int* __restrict__ ocnt,
                                                  const int* __restrict__ icnt,
                                                  float* __restrict__ zpart,
                                                  int fin) {
    __shared__ float wzs[4][8][8], wzd[4][8][8];
    int t = blockIdx.x * 256 + threadIdx.x;  // NN*DD/8 = 160000 threads exactly
    int n = t >> 3, ch = t & 7;
    int base = n * DD + ch * 8;
    float4 m0 = *(const float4*)(m + base);
    float4 m1 = *(const float4*)(m + base + 4);
    float4 h0 = *(const float4*)(h + base);
    float4 h1 = *(const float4*)(h + base + 4);
    float mv[8] = {m0.x, m0.y, m0.z, m0.w, m1.x, m1.y, m1.z, m1.w};
    float hv[8] = {h0.x, h0.y, h0.z, h0.w, h1.x, h1.y, h1.z, h1.w};
    unsigned short hbv[8];
#pragma unroll
    for (int q = 0; q < 8; ++q) {
        int col = ch * 8 + q;
        float v = sp_(hv[q] + mv[q] * coeffN[col] + coeffN[64 + col]);
        hv[q] = v;
        hbv[q] = f2b(v);
    }
    float4 o0, o1;
    o0.x = hv[0]; o0.y = hv[1]; o0.z = hv[2]; o0.w = hv[3];
    o1.x = hv[4]; o1.y = hv[5]; o1.z = hv[6]; o1.w = hv[7];
    *(float4*)(h + base) = o0;
    *(float4*)(h + base + 4) = o1;
    if (fin) return;  // pooling handled by pool_head_k from h

    bf16x8 hb8;
#pragma unroll
    for (int q = 0; q < 8; ++q) hb8[q] = (short)hbv[q];
    *(bf16x8*)(hb + base) = hb8;

    float oc = (float)ocnt[n], ic = (float)icnt[n];
    float zs8[8], zd8[8];
#pragma unroll
    for (int q = 0; q < 8; ++q) {
        float r = b2f(hbv[q]);
        zs8[q] = r * oc;
        zd8[q] = r * ic;
    }
#pragma unroll
    for (int mk = 8; mk <= 32; mk <<= 1) {
#pragma unroll
        for (int q = 0; q < 8; ++q) {
            zs8[q] += __shfl_xor(zs8[q], mk, 64);
            zd8[q] += __shfl_xor(zd8[q], mk, 64);
        }
    }
    int lane = threadIdx.x & 63;
    int w = threadIdx.x >> 6;
    if (lane < 8) {
#pragma unroll
        for (int q = 0; q < 8; ++q) {
            wzs[w][lane][q] = zs8[q];
            wzd[w][lane][q] = zd8[q];
        }
    }
    __syncthreads();
    if (threadIdx.x < 64) {
        int chh = threadIdx.x >> 3, qq = threadIdx.x & 7; // col = chh*8+qq = threadIdx.x
        float s = wzs[0][chh][qq] + wzs[1][chh][qq] + wzs[2][chh][qq] + wzs[3][chh][qq];
        float d = wzd[0][chh][qq] + wzd[1][chh][qq] + wzd[2][chh][qq] + wzd[3][chh][qq];
        zpart[(size_t)threadIdx.x * NHB + blockIdx.x] = s;
        zpart[(size_t)(64 + threadIdx.x) * NHB + blockIdx.x] = d;
    }
}

// ---------------- fused segmented pooling + head: one block per graph ----------------
__global__ __launch_bounds__(256) void pool_head_k(const float* __restrict__ h,
                                                   const int* __restrict__ gid,
                                                   const float* __restrict__ fcW,
                                                   const float* __restrict__ fcb,
                                                   const float* __restrict__ oW,
                                                   const float* __restrict__ ob,
                                                   float* __restrict__ out) {
    __shared__ int s_lo, s_hi;
    __shared__ float red4[4][DD];
    __shared__ float feats[DD];
    __shared__ float red[FF];
    int g = blockIdx.x;
    if (threadIdx.x == 0) {
        int lo = 0, hi = NN;
        while (lo < hi) { int mid = (lo + hi) >> 1; if (gid[mid] < g) lo = mid + 1; else hi = mid; }
        s_lo = lo;
        int lo2 = lo, hi2 = NN;
        while (lo2 < hi2) { int mid = (lo2 + hi2) >> 1; if (gid[mid] < g + 1) lo2 = mid + 1; else hi2 = mid; }
        s_hi = lo2;
    }
    __syncthreads();
    int lo = s_lo, hi = s_hi;
    int col = threadIdx.x & 63;
    int rr = threadIdx.x >> 6;
    float s = 0.f;
    for (int n = lo + rr; n < hi; n += 4) s += h[(size_t)n * DD + col];
    red4[rr][col] = s;
    __syncthreads();
    if (threadIdx.x < 64) {
        float v = red4[0][col] + red4[1][col] + red4[2][col] + red4[3][col];
        float c = fmaxf((float)(hi - lo), 1.f);
        feats[threadIdx.x] = sp_(v / c);
    }
    __syncthreads();
    if (threadIdx.x < FF) {
        int t = threadIdx.x;
        float a = fcb[t];
#pragma unroll 1
        for (int j = 0; j < DD; ++j) a += feats[j] * fcW[j * FF + t];
        float y = sp_(sp_(a));
        red[t] = y * oW[t];
    }
    __syncthreads();
    for (int s2 = 64; s2 >= 1; s2 >>= 1) {
        if (threadIdx.x < s2) red[threadIdx.x] += red[threadIdx.x + s2];
        __syncthreads();
    }
    if (threadIdx.x == 0) out[g] = red[0] + ob[0];
}

extern "C" void kernel_launch(void* const* d_in, const int* in_sizes, int n_in,
                              void* d_out, int out_size, void* d_ws, size_t ws_size,
                              hipStream_t stream) {
    const float* af   = (const float*)d_in[0];
    const float* bond = (const float*)d_in[1];
    const int*   src  = (const int*)d_in[2];
    const int*   dst  = (const int*)d_in[3];
    const int*   gid  = (const int*)d_in[4];
    const float* embW = (const float*)d_in[5];
    const float* embB = (const float*)d_in[6];
    const float* Wi   = (const float*)d_in[7];
    const float* gi   = (const float*)d_in[9];
    const float* bbi  = (const float*)d_in[10];
    const float* Wu   = (const float*)d_in[11];
    const float* gu   = (const float*)d_in[13];
    const float* bbu  = (const float*)d_in[14];
    const float* gn   = (const float*)d_in[15];
    const float* bbn  = (const float*)d_in[16];
    const float* fcW  = (const float*)d_in[17];
    const float* fcb  = (const float*)d_in[18];
    const float* oW   = (const float*)d_in[19];
    const float* ob   = (const float*)d_in[20];
    float* out = (float*)d_out;

    char* ws = (char*)d_ws;
    size_t off = 0;
    auto take = [&](size_t bytes) {
        size_t o = off;
        off += (bytes + 255) & ~(size_t)255;
        return o;
    };
    float* h     = (float*)(ws + take((size_t)NN * DD * 4));
    float* m     = (float*)(ws + take((size_t)NN * DD * 4));
    float* stats = (float*)(ws + take(516 * 4));  // [0..511] stats, [512] counter
    int* counter = (int*)(stats + 512);
    float* coeff = (float*)(ws + take(512 * 4)); // [sI2,tI2,sU2,tU2 | sN,tN]
    float* pq    = (float*)(ws + take((size_t)128 * NBLK * 4)); // 1.28 MB partial sumsq
    float* mpart = (float*)(ws + take((size_t)128 * NAB * 4));  // 640 KB m-stat partials
    float* zpart = (float*)(ws + take((size_t)128 * NHB * 4));  // 320 KB zsum partials
    int* ecount  = (int*)(ws + take((size_t)NN * 4));        // indeg
    int* ocount  = (int*)(ws + take((size_t)NN * 4));        // outdeg (contiguous after ecount)
    int* eoff    = (int*)(ws + take((size_t)(NN + 1) * 4));
    int* ecur    = (int*)(ws + take((size_t)NN * 4));
    int* ssrc    = (int*)(ws + take((size_t)NE * 4));
    int* sdst    = (int*)(ws + take((size_t)NE * 4));
    float* bond_s = (float*)(ws + take((size_t)NE * 4));
    unsigned short* hb    = (unsigned short*)(ws + take((size_t)NN * DD * 2));
    unsigned short* preIb = (unsigned short*)(ws + take((size_t)NE * DD * 2));
    unsigned short* preUb = (unsigned short*)(ws + take((size_t)NE * DD * 2));
    unsigned short* Wf    = (unsigned short*)(ws + take((size_t)6 * 10240 * 2));

    // zero: ecount+ocount (contiguous), stats incl. counter
    hipMemsetAsync((void*)ecount, 0, 2 * (((size_t)NN * 4 + 255) & ~(size_t)255), stream);
    hipMemsetAsync((void*)stats, 0, 516 * 4, stream);

    embed_k<<<NN / 32 + 6, 256, 0, stream>>>(af, embW, embB, h, hb, Wi, Wu, Wf);

    cnt_edges_k<<<(NE + 255) / 256, 256, 0, stream>>>(src, dst, ecount, ocount);
    csr_scan_k<<<1, 1024, 0, stream>>>(ecount, eoff, ecur);
    fill_edges_k<<<(NE + 255) / 256, 256, 0, stream>>>(src, dst, bond, ecur, ssrc, sdst, bond_s);
    rbfzsum_k<<<640, 256, 0, stream>>>(bond, hb, ocount, ecount, stats + 384, stats + 256,
                                       stats + 320);

    for (int l = 0; l < 3; ++l) {
        const unsigned short* Wfl = Wf + (size_t)l * 2 * 10240;
        edge_pre3_k<<<NBLK, 512, 0, stream>>>(hb, bond_s, Wfl, ssrc, sdst, preIb, preUb, pq);
        red2f_k<<<256, 256, 0, stream>>>(pq, zpart, stats, l > 0 ? 1 : 0, counter, Wfl,
                                         gi + l * DD, bbi + l * DD, gu + l * DD, bbu + l * DD,
                                         coeff);
        apply_node_k<<<NAB, 256, 0, stream>>>(preIb, preUb, eoff, coeff, m, mpart);
        fin_n3_k<<<64, 256, 0, stream>>>(mpart, gn + l * DD, bbn + l * DD, coeff + 256);
        h_update_k<<<NHB, 256, 0, stream>>>(h, hb, m, coeff + 256, ocount, ecount,
                                            zpart, l == 2 ? 1 : 0);
    }

    pool_head_k<<<NG, 256, 0, stream>>>(h, gid, fcW, fcb, oW, ob, out);
}

// Round 18
// 390.336 us; speedup vs baseline: 1.1573x; 1.1573x over previous
//
#include <hip/hip_runtime.h>
#include <hip/hip_bf16.h>
#include <math.h>

#define NN 20000
#define NE 320000
#define NG 128
#define DD 64
#define FA 92
#define FF 128
#define NT (NE / 16)          // 16-edge MFMA tiles = 20000
#define NBLK 2500             // edge_pre3 blocks (8 tiles/block, 1/wave, both gates)
#define NAB 1250              // apply_node blocks (16 threads/node)
#define NHB 625               // h_update blocks (NN*DD/8/256)
#define GAMMA 3.875f          // 31/8
#define CEN (8.0f / 31.0f)    // center spacing
#define L2E 1.44269504f
#define RBF2 (-GAMMA * L2E)   // exp(-g u^2) = exp2(u^2 * RBF2)

typedef __attribute__((ext_vector_type(8))) short bf16x8;
typedef __attribute__((ext_vector_type(4))) float f32x4;

// stats layout (floats): [0..127]=q(I|U), [256..383]=zsumS/zsumD, [384..415]=zsumR

__device__ __forceinline__ float sp_(float x) {
    return fmaxf(x, 0.f) + __logf(1.f + __expf(-fabsf(x)));
}
__device__ __forceinline__ unsigned short f2b(float x) {
    __hip_bfloat16 b = __float2bfloat16(x);
    return *reinterpret_cast<unsigned short*>(&b);
}
__device__ __forceinline__ float b2f(unsigned short u) {
    return __uint_as_float((unsigned)u << 16);
}

// halving tree: lane r (within 16-lane group) returns sum over group of v_orig[.][r]
__device__ __forceinline__ float tree16(float v[16], int r) {
#pragma unroll
    for (int m = 1; m < 16; m <<= 1) {
        bool b = (r & m) != 0;
        int cnt = 8 / m;   // outputs this step: 8,4,2,1
#pragma unroll
        for (int i = 0; i < cnt; ++i) {
            float keep = b ? v[2 * i + 1] : v[2 * i];
            float disc = b ? v[2 * i] : v[2 * i + 1];
            float recv = __shfl_xor(disc, m, 64);
            v[i] = keep + recv;
        }
    }
    return v[0];
}

// ---------------- embedding (blocks 0..624) + weight fragment prep (blocks 625..630) ----------------
__global__ __launch_bounds__(256) void embed_k(const float* __restrict__ af,
                                               const float* __restrict__ W,
                                               const float* __restrict__ b,
                                               float* __restrict__ h,
                                               unsigned short* __restrict__ hb,
                                               const float* __restrict__ Wi,
                                               const float* __restrict__ Wu,
                                               unsigned short* __restrict__ Wf) {
    if (blockIdx.x >= NN / 32) {
        int bb = blockIdx.x - NN / 32;   // 0..5 : layer*2 + gate
        int l = bb >> 1, g = bb & 1;
        const float* Wsrc = (g ? Wu : Wi) + (size_t)l * 160 * DD;
        for (int f = threadIdx.x; f < 10240; f += 256) {
            int i = f & 7;
            int lane = (f >> 3) & 63;
            int nf = (f >> 9) & 3;
            int kt = f >> 11;
            int k = kt * 32 + 8 * (lane >> 4) + i;
            int col = nf * 16 + (lane & 15);
            Wf[(size_t)bb * 10240 + f] = f2b(Wsrc[k * DD + col]);
        }
        return;
    }
    __shared__ float Ws[FA * DD];   // 23552 B
    __shared__ float afS[32][FA];   // 11776 B
    const int n0 = blockIdx.x * 32;
    for (int i = threadIdx.x * 4; i < FA * DD; i += 256 * 4)
        *(float4*)&Ws[i] = *(const float4*)&W[i];
    const float4* af4 = (const float4*)(af + (size_t)n0 * FA);
    for (int i = threadIdx.x; i < 32 * FA / 4; i += 256) {
        float4 v = af4[i];
        int nl = i / (FA / 4), kk = (i % (FA / 4)) * 4;
        *(float4*)&afS[nl][kk] = v;
    }
    __syncthreads();
    int nl = threadIdx.x >> 3, ch = threadIdx.x & 7;
    int n = n0 + nl;
    float acc[8];
#pragma unroll
    for (int q = 0; q < 8; ++q) acc[q] = b[ch * 8 + q];
#pragma unroll 4
    for (int k = 0; k < FA; ++k) {
        float a = afS[nl][k];
        const float* wr = &Ws[k * DD + ch * 8];
        float4 w0 = *(const float4*)wr;
        float4 w1 = *(const float4*)(wr + 4);
        acc[0] += a * w0.x; acc[1] += a * w0.y; acc[2] += a * w0.z; acc[3] += a * w0.w;
        acc[4] += a * w1.x; acc[5] += a * w1.y; acc[6] += a * w1.z; acc[7] += a * w1.w;
    }
    float* o = h + (size_t)n * DD + ch * 8;
    float4 o0, o1;
    o0.x = acc[0]; o0.y = acc[1]; o0.z = acc[2]; o0.w = acc[3];
    o1.x = acc[4]; o1.y = acc[5]; o1.z = acc[6]; o1.w = acc[7];
    *(float4*)o = o0;
    *(float4*)(o + 4) = o1;
    bf16x8 hb8;
#pragma unroll
    for (int q = 0; q < 8; ++q) hb8[q] = (short)f2b(acc[q]);
    *(bf16x8*)(hb + (size_t)n * DD + ch * 8) = hb8;
}

// ---------------- CSR build (sorted-by-dst edge order) ----------------
__global__ void cnt_edges_k(const int* __restrict__ src, const int* __restrict__ dst,
                            int* __restrict__ icnt, int* __restrict__ ocnt) {
    int e = blockIdx.x * 256 + threadIdx.x;
    if (e < NE) {
        atomicAdd(&icnt[dst[e]], 1);
        atomicAdd(&ocnt[src[e]], 1);
    }
}

__global__ __launch_bounds__(1024) void csr_scan_k(const int* __restrict__ cnt,
                                                   int* __restrict__ off,
                                                   int* __restrict__ cur) {
    __shared__ int part[1024];
    int t = threadIdx.x;
    int base = t * 20;
    int s = 0;
    for (int i = 0; i < 20; ++i) { int idx = base + i; if (idx < NN) s += cnt[idx]; }
    part[t] = s;
    __syncthreads();
    for (int ofs = 1; ofs < 1024; ofs <<= 1) {
        int v = (t >= ofs) ? part[t - ofs] : 0;
        __syncthreads();
        part[t] += v;
        __syncthreads();
    }
    int run = (t == 0) ? 0 : part[t - 1];
    for (int i = 0; i < 20; ++i) {
        int idx = base + i;
        if (idx < NN) { off[idx] = run; cur[idx] = run; run += cnt[idx]; }
    }
    if (t == 1023) off[NN] = run;
}

__global__ void fill_edges_k(const int* __restrict__ src, const int* __restrict__ dst,
                             const float* __restrict__ bond,
                             int* __restrict__ cur, int* __restrict__ ssrc,
                             int* __restrict__ sdst, float* __restrict__ bond_s) {
    int e = blockIdx.x * 256 + threadIdx.x;
    if (e < NE) {
        int d = dst[e];
        int p = atomicAdd(&cur[d], 1);
        ssrc[p] = src[e];
        sdst[p] = d;
        bond_s[p] = bond[e];
    }
}

// ---------------- fused one-time stats: rbf col-sums (blocks <512) + zsum (blocks >=512) ----------------
__global__ __launch_bounds__(256) void rbfzsum_k(const float* __restrict__ bond,
                                                 const unsigned short* __restrict__ hb,
                                                 const int* __restrict__ ocnt,
                                                 const int* __restrict__ icnt,
                                                 float* __restrict__ zr,
                                                 float* __restrict__ zS,
                                                 float* __restrict__ zD) {
    if (blockIdx.x < 512) {
        __shared__ float part[4][32];
        int lane = threadIdx.x & 63;
        int w = threadIdx.x >> 6;
        int col = lane & 31;
        int half = lane >> 5;
        int slot = (blockIdx.x * 4 + w) * 2 + half;
        int nslots = 512 * 8;
        float cen = (float)col * CEN;
        float a = 0.f;
        for (int e = slot; e < NE; e += nslots) {
            float u = bond[e] - cen;
            a += b2f(f2b(__builtin_amdgcn_exp2f(u * u * RBF2)));
        }
        a += __shfl_xor(a, 32, 64);
        if (half == 0) part[w][col] = a;
        __syncthreads();
        if (threadIdx.x < 32) {
            float s = part[0][threadIdx.x] + part[1][threadIdx.x] +
                      part[2][threadIdx.x] + part[3][threadIdx.x];
            unsafeAtomicAdd(&zr[threadIdx.x], s);
        }
    } else {
        int bb = blockIdx.x - 512;  // 0..127
        int t = bb * 256 + threadIdx.x;
        int col = t & 63;
        int n0 = t >> 6;
        int nstride = (128 * 256) >> 6;
        float aS = 0.f, aD = 0.f;
        for (int n = n0; n < NN; n += nstride) {
            float v = b2f(hb[(size_t)n * DD + col]);
            aS += (float)ocnt[n] * v;
            aD += (float)icnt[n] * v;
        }
        unsafeAtomicAdd(&zS[col], aS);
        unsafeAtomicAdd(&zD[col], aD);
    }
}

// ---------------- gather-GEMM, BOTH gates, 512 thr, 40KB LDS, coalesced stores via LDS repack ----------------
__global__ __launch_bounds__(512, 8) void edge_pre3_k(const unsigned short* __restrict__ hb,
                                                      const float* __restrict__ bond_s,
                                                      const unsigned short* __restrict__ Wf, // layer base [2][10240]
                                                      const int* __restrict__ ssrc,
                                                      const int* __restrict__ sdst,
                                                      unsigned short* __restrict__ preIb,
                                                      unsigned short* __restrict__ preUb,
                                                      float* __restrict__ pq) {
    __shared__ bf16x8 WfS[2560];      // 40960 B : both gates; gate-I region reused as repack slots + qred
    unsigned short* tbuf = (unsigned short*)WfS;  // repack slots: wave w at ushort offset w*1152 (16 rows x 72)
    float* qred = (float*)WfS;
    const int bidx = blockIdx.x;      // 0..NBLK-1
    const int lane = threadIdx.x & 63;
    const int w = threadIdx.x >> 6;   // 0..7
    const int r = lane & 15;          // edge-within-tile
    const int c = lane >> 4;          // k-chunk
    const int tile = bidx * 8 + w;    // exactly NT tiles
    const int e = tile * 16 + r;

    int es = ssrc[e];
    int ed = sdst[e];
    float bd = bond_s[e];
    bf16x8 a0 = *(const bf16x8*)(hb + (size_t)es * DD + c * 8);
    bf16x8 a1 = *(const bf16x8*)(hb + (size_t)es * DD + 32 + c * 8);
    bf16x8 a2 = *(const bf16x8*)(hb + (size_t)ed * DD + c * 8);
    bf16x8 a3 = *(const bf16x8*)(hb + (size_t)ed * DD + 32 + c * 8);
    bf16x8 a4;
#pragma unroll
    for (int i = 0; i < 8; ++i) {
        float u = bd - (float)(8 * c + i) * CEN;
        a4[i] = (short)f2b(__builtin_amdgcn_exp2f(u * u * RBF2));
    }

    {
        const bf16x8* Wf8 = (const bf16x8*)Wf;
        for (int i = threadIdx.x; i < 2560; i += 512) WfS[i] = Wf8[i];
    }
    __syncthreads();

    float qI[16], qU[16];
    // gate I
    f32x4 accI[4];
    {
#pragma unroll
        for (int nf = 0; nf < 4; ++nf) { f32x4 z4 = {0.f, 0.f, 0.f, 0.f}; accI[nf] = z4; }
#pragma unroll
        for (int kt = 0; kt < 5; ++kt) {
            bf16x8 a = (kt == 0) ? a0 : (kt == 1) ? a1 : (kt == 2) ? a2 : (kt == 3) ? a3 : a4;
#pragma unroll
            for (int nf = 0; nf < 4; ++nf)
                accI[nf] = __builtin_amdgcn_mfma_f32_16x16x32_bf16(WfS[(kt * 4 + nf) * 64 + lane], a, accI[nf], 0, 0, 0);
        }
#pragma unroll
        for (int nf = 0; nf < 4; ++nf)
#pragma unroll
            for (int j = 0; j < 4; ++j) qI[nf * 4 + j] = accI[nf][j] * accI[nf][j];
    }
    __syncthreads();   // all waves done with gate-I weights -> slots usable

    unsigned short* slot = tbuf + w * 1152;   // 16 rows x 72 ushorts (144 B, 16B-aligned)
    // repack + coalesced store, gate I
    {
#pragma unroll
        for (int nf = 0; nf < 4; ++nf) {
            ushort4 o;
            o.x = f2b(accI[nf][0]); o.y = f2b(accI[nf][1]);
            o.z = f2b(accI[nf][2]); o.w = f2b(accI[nf][3]);
            *(ushort4*)(slot + r * 72 + c * 4 + nf * 16) = o;
        }
        bf16x8 v0 = *(const bf16x8*)(slot + (lane >> 2) * 72 + (lane & 3) * 16);
        bf16x8 v1 = *(const bf16x8*)(slot + (lane >> 2) * 72 + (lane & 3) * 16 + 8);
        unsigned short* dst0 = preIb + (size_t)tile * 1024 + lane * 16;
        *(bf16x8*)dst0 = v0;
        *(bf16x8*)(dst0 + 8) = v1;
    }
    // gate U (reuses a0..a4 in registers; gate-U weights untouched at WfS[1280..])
    {
        f32x4 acc[4];
#pragma unroll
        for (int nf = 0; nf < 4; ++nf) { f32x4 z4 = {0.f, 0.f, 0.f, 0.f}; acc[nf] = z4; }
#pragma unroll
        for (int kt = 0; kt < 5; ++kt) {
            bf16x8 a = (kt == 0) ? a0 : (kt == 1) ? a1 : (kt == 2) ? a2 : (kt == 3) ? a3 : a4;
#pragma unroll
            for (int nf = 0; nf < 4; ++nf)
                acc[nf] = __builtin_amdgcn_mfma_f32_16x16x32_bf16(WfS[1280 + (kt * 4 + nf) * 64 + lane], a, acc[nf], 0, 0, 0);
        }
#pragma unroll
        for (int nf = 0; nf < 4; ++nf) {
            ushort4 o;
            o.x = f2b(acc[nf][0]); o.y = f2b(acc[nf][1]);
            o.z = f2b(acc[nf][2]); o.w = f2b(acc[nf][3]);
            *(ushort4*)(slot + r * 72 + c * 4 + nf * 16) = o;
#pragma unroll
            for (int j = 0; j < 4; ++j) qU[nf * 4 + j] = acc[nf][j] * acc[nf][j];
        }
        bf16x8 v0 = *(const bf16x8*)(slot + (lane >> 2) * 72 + (lane & 3) * 16);
        bf16x8 v1 = *(const bf16x8*)(slot + (lane >> 2) * 72 + (lane & 3) * 16 + 8);
        unsigned short* dst0 = preUb + (size_t)tile * 1024 + lane * 16;
        *(bf16x8*)dst0 = v0;
        *(bf16x8*)(dst0 + 8) = v1;
    }

    // sumsq reduce across the 16 r-lanes (halving tree); then cross-wave via aliased LDS
    float vI = tree16(qI, r);
    float vU = tree16(qU, r);
    int col = (r >> 2) * 16 + c * 4 + (r & 3);
    __syncthreads();   // all waves done with their slots -> qred region safe
    qred[w * 128 + col] = vI;
    qred[w * 128 + 64 + col] = vU;
    __syncthreads();
    if (threadIdx.x < 128) {
        float s8 = 0.f;
#pragma unroll
        for (int ww = 0; ww < 8; ++ww) s8 += qred[ww * 128 + threadIdx.x];
        pq[(size_t)threadIdx.x * NBLK + bidx] = s8;  // rows: 0..63 = qI, 64..127 = qU
    }
}

// ---------------- fused reduce: pq(len NBLK) -> stats[0..127], zpart(len NHB) -> stats[256..383] ----------------
__global__ __launch_bounds__(256) void red2_k(const float* __restrict__ pq,
                                              const float* __restrict__ zpart,
                                              float* __restrict__ stats, int withz) {
    __shared__ float red[256];
    int b = blockIdx.x;
    const float* row;
    float* out;
    int len;
    if (b < 128) { row = pq + (size_t)b * NBLK; out = &stats[b]; len = NBLK; }
    else {
        if (!withz) return;
        row = zpart + (size_t)(b - 128) * NHB; out = &stats[256 + (b - 128)]; len = NHB;
    }
    float s = 0.f;
    for (int i = threadIdx.x; i < len; i += 256) s += row[i];
    red[threadIdx.x] = s;
    __syncthreads();
    for (int ofs = 128; ofs >= 1; ofs >>= 1) {
        if (threadIdx.x < ofs) red[threadIdx.x] += red[threadIdx.x + ofs];
        __syncthreads();
    }
    if (threadIdx.x == 0) *out = red[0];
}

// ---------------- BN coeffs gate/update (256 thr: 4-way k-split + LDS reduce) ----------------
// coeff emitted with log2e folded: [0]=-L2E*sI, [64]=-L2E*tI, [128]=L2E*sU, [192]=L2E*tU
__global__ __launch_bounds__(256) void fin_iu_k(const float* __restrict__ stats,
                                                const unsigned short* __restrict__ Wf,
                                                const float* __restrict__ gi, const float* __restrict__ bbi,
                                                const float* __restrict__ gu, const float* __restrict__ bbu,
                                                float* __restrict__ coeff) {
    __shared__ float redI[256], redU[256];
    int t = threadIdx.x;
    int j = t & 63, part = t >> 6;  // 4 parts
    int nf = j >> 4, rr = j & 15;
    float muI = 0.f, muU = 0.f;
    for (int k = part; k < 160; k += 4) {
        float zs = (k < 128) ? stats[256 + k] : stats[384 + k - 128];
        int kt = k >> 5, rem = k & 31, cc = rem >> 3, ii = rem & 7;
        int f = kt * 2048 + nf * 512 + (cc * 16 + rr) * 8 + ii;
        muI += zs * b2f(Wf[f]);
        muU += zs * b2f(Wf[10240 + f]);
    }
    redI[t] = muI;
    redU[t] = muU;
    __syncthreads();
    if (t < 64) {
        muI = redI[t] + redI[64 + t] + redI[128 + t] + redI[192 + t];
        muU = redU[t] + redU[64 + t] + redU[128 + t] + redU[192 + t];
        const float invE = 1.f / (float)NE;
        muI *= invE; muU *= invE;
        float varI = stats[t] * invE - muI * muI;
        float sI = gi[t] * rsqrtf(varI + 1e-5f);
        float tI = bbi[t] - muI * sI;
        float varU = stats[64 + t] * invE - muU * muU;
        float sU = gu[t] * rsqrtf(varU + 1e-5f);
        float tU = bbu[t] - muU * sU;
        coeff[t]       = -L2E * sI;
        coeff[64 + t]  = -L2E * tI;
        coeff[128 + t] =  L2E * sU;
        coeff[192 + t] =  L2E * tU;
    }
}

// ---------------- node-parallel apply (16 thr/node, x8 loads) + fused m stats ----------------
// act = log(1+2^xu') * rcp(1+2^xi')  — global ln2 factor dropped (BN scale-invariant)
__global__ __launch_bounds__(256) void apply_node_k(const unsigned short* __restrict__ preIb,
                                                    const unsigned short* __restrict__ preUb,
                                                    const int* __restrict__ eoff,
                                                    const float* __restrict__ coeff,
                                                    float* __restrict__ m,
                                                    float* __restrict__ mpart) {
    __shared__ float ps[128][8];
    __shared__ float pq2[128][8];
    int ch = threadIdx.x & 7;
    int half = (threadIdx.x >> 3) & 1;
    int nl = threadIdx.x >> 4;              // 0..15
    int n = blockIdx.x * 16 + nl;
    float sIv[8], tIv[8], sUv[8], tUv[8];
#pragma unroll
    for (int q = 0; q < 8; ++q) {
        int col = ch * 8 + q;
        sIv[q] = coeff[col];       tIv[q] = coeff[64 + col];
        sUv[q] = coeff[128 + col]; tUv[q] = coeff[192 + col];
    }
    int b = eoff[n], e = eoff[n + 1];
    float acc[8];
#pragma unroll
    for (int q = 0; q < 8; ++q) acc[q] = 0.f;
    for (int p = b + half; p < e; p += 2) {
        bf16x8 vi = *(const bf16x8*)(preIb + (size_t)p * DD + ch * 8);
        bf16x8 vu = *(const bf16x8*)(preUb + (size_t)p * DD + ch * 8);
#pragma unroll
        for (int q = 0; q < 8; ++q) {
            float xi = fmaf(b2f((unsigned short)vi[q]), sIv[q], tIv[q]);
            float den = 1.f + __builtin_amdgcn_exp2f(xi);
            float xu = fmaf(b2f((unsigned short)vu[q]), sUv[q], tUv[q]);
            float lu = __builtin_amdgcn_logf(1.f + __builtin_amdgcn_exp2f(xu));
            acc[q] = fmaf(lu, __builtin_amdgcn_rcpf(den), acc[q]);
        }
    }
#pragma unroll
    for (int q = 0; q < 8; ++q) acc[q] += __shfl_xor(acc[q], 8, 64);
    if (half == 0) {
        float* mp = m + (size_t)n * DD + ch * 8;
        float4 v0, v1;
        v0.x = acc[0]; v0.y = acc[1]; v0.z = acc[2]; v0.w = acc[3];
        v1.x = acc[4]; v1.y = acc[5]; v1.z = acc[6]; v1.w = acc[7];
        *(float4*)mp = v0;
        *(float4*)(mp + 4) = v1;
        int idx = nl * 8 + ch;  // 0..127
#pragma unroll
        for (int q = 0; q < 8; ++q) {
            ps[idx][q] = acc[q];
            pq2[idx][q] = acc[q] * acc[q];
        }
    }
    __syncthreads();
    if (threadIdx.x < 64) {
        int j = threadIdx.x;
        int chh = j >> 3, qq = j & 7;
        float s = 0.f, q2 = 0.f;
#pragma unroll
        for (int nn = 0; nn < 16; ++nn) {
            s += ps[nn * 8 + chh][qq];
            q2 += pq2[nn * 8 + chh][qq];
        }
        mpart[(size_t)j * NAB + blockIdx.x] = s;
        mpart[(size_t)(64 + j) * NAB + blockIdx.x] = q2;
    }
}

// ---------------- fused mpart reduce + BN(m) coeffs: 64 blocks, block j -> col j ----------------
__global__ __launch_bounds__(256) void fin_n3_k(const float* __restrict__ mpart,
                                                const float* __restrict__ gn,
                                                const float* __restrict__ bbn,
                                                float* __restrict__ coeffN) {
    __shared__ float red1[256], red2[256];
    int j = blockIdx.x; // 0..63
    float s1 = 0.f, s2 = 0.f;
    for (int i = threadIdx.x; i < NAB; i += 256) {
        s1 += mpart[(size_t)j * NAB + i];
        s2 += mpart[(size_t)(64 + j) * NAB + i];
    }
    red1[threadIdx.x] = s1;
    red2[threadIdx.x] = s2;
    __syncthreads();
    for (int ofs = 128; ofs >= 1; ofs >>= 1) {
        if (threadIdx.x < ofs) {
            red1[threadIdx.x] += red1[threadIdx.x + ofs];
            red2[threadIdx.x] += red2[threadIdx.x + ofs];
        }
        __syncthreads();
    }
    if (threadIdx.x == 0) {
        const float invN = 1.f / (float)NN;
        float mu = red1[0] * invN;
        float var = red2[0] * invN - mu * mu;
        float sc = gn[j] * rsqrtf(var + 1e-5f);
        coeffN[j] = sc;
        coeffN[64 + j] = bbn[j] - mu * sc;
    }
}

// ---------------- h = sp(h + bn(m)), 8-wide; non-fin fuses next-layer zsum partials ----------------
__global__ __launch_bounds__(256) void h_update_k(float* __restrict__ h,
                                                  unsigned short* __restrict__ hb,
                                                  const float* __restrict__ m,
                                                  const float* __restrict__ coeffN,
                                                  const int* __restrict__ ocnt,
                                                  const int* __restrict__ icnt,
                                                  float* __restrict__ zpart,
                                                  int fin) {
    __shared__ float wzs[4][8][8], wzd[4][8][8];
    int t = blockIdx.x * 256 + threadIdx.x;  // NN*DD/8 = 160000 threads exactly
    int n = t >> 3, ch = t & 7;
    int base = n * DD + ch * 8;
    float4 m0 = *(const float4*)(m + base);
    float4 m1 = *(const float4*)(m + base + 4);
    float4 h0 = *(const float4*)(h + base);
    float4 h1 = *(const float4*)(h + base + 4);
    float mv[8] = {m0.x, m0.y, m0.z, m0.w, m1.x, m1.y, m1.z, m1.w};
    float hv[8] = {h0.x, h0.y, h0.z, h0.w, h1.x, h1.y, h1.z, h1.w};
    unsigned short hbv[8];
#pragma unroll
    for (int q = 0; q < 8; ++q) {
        int col = ch * 8 + q;
        float v = sp_(hv[q] + mv[q] * coeffN[col] + coeffN[64 + col]);
        hv[q] = v;
        hbv[q] = f2b(v);
    }
    float4 o0, o1;
    o0.x = hv[0]; o0.y = hv[1]; o0.z = hv[2]; o0.w = hv[3];
    o1.x = hv[4]; o1.y = hv[5]; o1.z = hv[6]; o1.w = hv[7];
    *(float4*)(h + base) = o0;
    *(float4*)(h + base + 4) = o1;
    if (fin) return;  // pooling handled by pool_head_k from h

    bf16x8 hb8;
#pragma unroll
    for (int q = 0; q < 8; ++q) hb8[q] = (short)hbv[q];
    *(bf16x8*)(hb + base) = hb8;

    float oc = (float)ocnt[n], ic = (float)icnt[n];
    float zs8[8], zd8[8];
#pragma unroll
    for (int q = 0; q < 8; ++q) {
        float r = b2f(hbv[q]);
        zs8[q] = r * oc;
        zd8[q] = r * ic;
    }
#pragma unroll
    for (int mk = 8; mk <= 32; mk <<= 1) {
#pragma unroll
        for (int q = 0; q < 8; ++q) {
            zs8[q] += __shfl_xor(zs8[q], mk, 64);
            zd8[q] += __shfl_xor(zd8[q], mk, 64);
        }
    }
    int lane = threadIdx.x & 63;
    int w = threadIdx.x >> 6;
    if (lane < 8) {
#pragma unroll
        for (int q = 0; q < 8; ++q) {
            wzs[w][lane][q] = zs8[q];
            wzd[w][lane][q] = zd8[q];
        }
    }
    __syncthreads();
    if (threadIdx.x < 64) {
        int chh = threadIdx.x >> 3, qq = threadIdx.x & 7; // col = chh*8+qq = threadIdx.x
        float s = wzs[0][chh][qq] + wzs[1][chh][qq] + wzs[2][chh][qq] + wzs[3][chh][qq];
        float d = wzd[0][chh][qq] + wzd[1][chh][qq] + wzd[2][chh][qq] + wzd[3][chh][qq];
        zpart[(size_t)threadIdx.x * NHB + blockIdx.x] = s;
        zpart[(size_t)(64 + threadIdx.x) * NHB + blockIdx.x] = d;
    }
}

// ---------------- fused segmented pooling + head: one block per graph ----------------
__global__ __launch_bounds__(256) void pool_head_k(const float* __restrict__ h,
                                                   const int* __restrict__ gid,
                                                   const float* __restrict__ fcW,
                                                   const float* __restrict__ fcb,
                                                   const float* __restrict__ oW,
                                                   const float* __restrict__ ob,
                                                   float* __restrict__ out) {
    __shared__ int s_lo, s_hi;
    __shared__ float red4[4][DD];
    __shared__ float feats[DD];
    __shared__ float red[FF];
    int g = blockIdx.x;
    if (threadIdx.x == 0) {
        int lo = 0, hi = NN;
        while (lo < hi) { int mid = (lo + hi) >> 1; if (gid[mid] < g) lo = mid + 1; else hi = mid; }
        s_lo = lo;
        int lo2 = lo, hi2 = NN;
        while (lo2 < hi2) { int mid = (lo2 + hi2) >> 1; if (gid[mid] < g + 1) lo2 = mid + 1; else hi2 = mid; }
        s_hi = lo2;
    }
    __syncthreads();
    int lo = s_lo, hi = s_hi;
    int col = threadIdx.x & 63;
    int rr = threadIdx.x >> 6;
    float s = 0.f;
    for (int n = lo + rr; n < hi; n += 4) s += h[(size_t)n * DD + col];
    red4[rr][col] = s;
    __syncthreads();
    if (threadIdx.x < 64) {
        float v = red4[0][col] + red4[1][col] + red4[2][col] + red4[3][col];
        float c = fmaxf((float)(hi - lo), 1.f);
        feats[threadIdx.x] = sp_(v / c);
    }
    __syncthreads();
    if (threadIdx.x < FF) {
        int t = threadIdx.x;
        float a = fcb[t];
#pragma unroll 1
        for (int j = 0; j < DD; ++j) a += feats[j] * fcW[j * FF + t];
        float y = sp_(sp_(a));
        red[t] = y * oW[t];
    }
    __syncthreads();
    for (int s2 = 64; s2 >= 1; s2 >>= 1) {
        if (threadIdx.x < s2) red[threadIdx.x] += red[threadIdx.x + s2];
        __syncthreads();
    }
    if (threadIdx.x == 0) out[g] = red[0] + ob[0];
}

extern "C" void kernel_launch(void* const* d_in, const int* in_sizes, int n_in,
                              void* d_out, int out_size, void* d_ws, size_t ws_size,
                              hipStream_t stream) {
    const float* af   = (const float*)d_in[0];
    const float* bond = (const float*)d_in[1];
    const int*   src  = (const int*)d_in[2];
    const int*   dst  = (const int*)d_in[3];
    const int*   gid  = (const int*)d_in[4];
    const float* embW = (const float*)d_in[5];
    const float* embB = (const float*)d_in[6];
    const float* Wi   = (const float*)d_in[7];
    const float* gi   = (const float*)d_in[9];
    const float* bbi  = (const float*)d_in[10];
    const float* Wu   = (const float*)d_in[11];
    const float* gu   = (const float*)d_in[13];
    const float* bbu  = (const float*)d_in[14];
    const float* gn   = (const float*)d_in[15];
    const float* bbn  = (const float*)d_in[16];
    const float* fcW  = (const float*)d_in[17];
    const float* fcb  = (const float*)d_in[18];
    const float* oW   = (const float*)d_in[19];
    const float* ob   = (const float*)d_in[20];
    float* out = (float*)d_out;

    char* ws = (char*)d_ws;
    size_t off = 0;
    auto take = [&](size_t bytes) {
        size_t o = off;
        off += (bytes + 255) & ~(size_t)255;
        return o;
    };
    float* h     = (float*)(ws + take((size_t)NN * DD * 4));
    float* m     = (float*)(ws + take((size_t)NN * DD * 4));
    float* stats = (float*)(ws + take(512 * 4));
    float* coeff = (float*)(ws + take(512 * 4)); // [sI2,tI2,sU2,tU2 | sN,tN]
    float* pq    = (float*)(ws + take((size_t)128 * NBLK * 4)); // 1.28 MB partial sumsq
    float* mpart = (float*)(ws + take((size_t)128 * NAB * 4));  // 640 KB m-stat partials
    float* zpart = (float*)(ws + take((size_t)128 * NHB * 4));  // 320 KB zsum partials
    int* ecount  = (int*)(ws + take((size_t)NN * 4));        // indeg
    int* ocount  = (int*)(ws + take((size_t)NN * 4));        // outdeg (contiguous after ecount)
    int* eoff    = (int*)(ws + take((size_t)(NN + 1) * 4));
    int* ecur    = (int*)(ws + take((size_t)NN * 4));
    int* ssrc    = (int*)(ws + take((size_t)NE * 4));
    int* sdst    = (int*)(ws + take((size_t)NE * 4));
    float* bond_s = (float*)(ws + take((size_t)NE * 4));
    unsigned short* hb    = (unsigned short*)(ws + take((size_t)NN * DD * 2));
    unsigned short* preIb = (unsigned short*)(ws + take((size_t)NE * DD * 2));
    unsigned short* preUb = (unsigned short*)(ws + take((size_t)NE * DD * 2));
    unsigned short* Wf    = (unsigned short*)(ws + take((size_t)6 * 10240 * 2));

    // zero: ecount+ocount (contiguous), stats
    hipMemsetAsync((void*)ecount, 0, 2 * (((size_t)NN * 4 + 255) & ~(size_t)255), stream);
    hipMemsetAsync((void*)stats, 0, 512 * 4, stream);

    embed_k<<<NN / 32 + 6, 256, 0, stream>>>(af, embW, embB, h, hb, Wi, Wu, Wf);

    cnt_edges_k<<<(NE + 255) / 256, 256, 0, stream>>>(src, dst, ecount, ocount);
    csr_scan_k<<<1, 1024, 0, stream>>>(ecount, eoff, ecur);
    fill_edges_k<<<(NE + 255) / 256, 256, 0, stream>>>(src, dst, bond, ecur, ssrc, sdst, bond_s);
    rbfzsum_k<<<640, 256, 0, stream>>>(bond, hb, ocount, ecount, stats + 384, stats + 256,
                                       stats + 320);

    for (int l = 0; l < 3; ++l) {
        const unsigned short* Wfl = Wf + (size_t)l * 2 * 10240;
        edge_pre3_k<<<NBLK, 512, 0, stream>>>(hb, bond_s, Wfl, ssrc, sdst, preIb, preUb, pq);
        red2_k<<<256, 256, 0, stream>>>(pq, zpart, stats, l > 0 ? 1 : 0);
        fin_iu_k<<<1, 256, 0, stream>>>(stats, Wfl, gi + l * DD, bbi + l * DD,
                                        gu + l * DD, bbu + l * DD, coeff);
        apply_node_k<<<NAB, 256, 0, stream>>>(preIb, preUb, eoff, coeff, m, mpart);
        fin_n3_k<<<64, 256, 0, stream>>>(mpart, gn + l * DD, bbn + l * DD, coeff + 256);
        h_update_k<<<NHB, 256, 0, stream>>>(h, hb, m, coeff + 256, ocount, ecount,
                                            zpart, l == 2 ? 1 : 0);
    }

    pool_head_k<<<NG, 256, 0, stream>>>(h, gid, fcW, fcb, oW, ob, out);
}

// Round 19
// 389.143 us; speedup vs baseline: 1.1608x; 1.0031x over previous
//
#include <hip/hip_runtime.h>
#include <hip/hip_bf16.h>
#include <math.h>

#define NN 20000
#define NE 320000
#define NG 128
#define DD 64
#define FA 92
#define FF 128
#define NT (NE / 16)          // 16-edge MFMA tiles = 20000
#define NBLK 2500             // edge_pre3 blocks (8 tiles/block, 1/wave, both gates)
#define NAB 2500              // apply_node blocks (32 threads/node, 8 nodes/block)
#define NHB 625               // h_update blocks (NN*DD/8/256)
#define GAMMA 3.875f          // 31/8
#define CEN (8.0f / 31.0f)    // center spacing
#define L2E 1.44269504f
#define RBF2 (-GAMMA * L2E)   // exp(-g u^2) = exp2(u^2 * RBF2)

typedef __attribute__((ext_vector_type(8))) short bf16x8;
typedef __attribute__((ext_vector_type(4))) float f32x4;

// stats layout (floats): [0..127]=q(I|U), [256..383]=zsumS/zsumD, [384..415]=zsumR

__device__ __forceinline__ float sp_(float x) {
    return fmaxf(x, 0.f) + __logf(1.f + __expf(-fabsf(x)));
}
__device__ __forceinline__ unsigned short f2b(float x) {
    __hip_bfloat16 b = __float2bfloat16(x);
    return *reinterpret_cast<unsigned short*>(&b);
}
__device__ __forceinline__ float b2f(unsigned short u) {
    return __uint_as_float((unsigned)u << 16);
}

// halving tree: lane r (within 16-lane group) returns sum over group of v_orig[.][r]
__device__ __forceinline__ float tree16(float v[16], int r) {
#pragma unroll
    for (int m = 1; m < 16; m <<= 1) {
        bool b = (r & m) != 0;
        int cnt = 8 / m;   // outputs this step: 8,4,2,1
#pragma unroll
        for (int i = 0; i < cnt; ++i) {
            float keep = b ? v[2 * i + 1] : v[2 * i];
            float disc = b ? v[2 * i] : v[2 * i + 1];
            float recv = __shfl_xor(disc, m, 64);
            v[i] = keep + recv;
        }
    }
    return v[0];
}

// ---------------- embedding (blocks 0..624) + weight fragment prep (blocks 625..630) ----------------
__global__ __launch_bounds__(256) void embed_k(const float* __restrict__ af,
                                               const float* __restrict__ W,
                                               const float* __restrict__ b,
                                               float* __restrict__ h,
                                               unsigned short* __restrict__ hb,
                                               const float* __restrict__ Wi,
                                               const float* __restrict__ Wu,
                                               unsigned short* __restrict__ Wf) {
    if (blockIdx.x >= NN / 32) {
        int bb = blockIdx.x - NN / 32;   // 0..5 : layer*2 + gate
        int l = bb >> 1, g = bb & 1;
        const float* Wsrc = (g ? Wu : Wi) + (size_t)l * 160 * DD;
        for (int f = threadIdx.x; f < 10240; f += 256) {
            int i = f & 7;
            int lane = (f >> 3) & 63;
            int nf = (f >> 9) & 3;
            int kt = f >> 11;
            int k = kt * 32 + 8 * (lane >> 4) + i;
            int col = nf * 16 + (lane & 15);
            Wf[(size_t)bb * 10240 + f] = f2b(Wsrc[k * DD + col]);
        }
        return;
    }
    __shared__ float Ws[FA * DD];   // 23552 B
    __shared__ float afS[32][FA];   // 11776 B
    const int n0 = blockIdx.x * 32;
    for (int i = threadIdx.x * 4; i < FA * DD; i += 256 * 4)
        *(float4*)&Ws[i] = *(const float4*)&W[i];
    const float4* af4 = (const float4*)(af + (size_t)n0 * FA);
    for (int i = threadIdx.x; i < 32 * FA / 4; i += 256) {
        float4 v = af4[i];
        int nl = i / (FA / 4), kk = (i % (FA / 4)) * 4;
        *(float4*)&afS[nl][kk] = v;
    }
    __syncthreads();
    int nl = threadIdx.x >> 3, ch = threadIdx.x & 7;
    int n = n0 + nl;
    float acc[8];
#pragma unroll
    for (int q = 0; q < 8; ++q) acc[q] = b[ch * 8 + q];
#pragma unroll 4
    for (int k = 0; k < FA; ++k) {
        float a = afS[nl][k];
        const float* wr = &Ws[k * DD + ch * 8];
        float4 w0 = *(const float4*)wr;
        float4 w1 = *(const float4*)(wr + 4);
        acc[0] += a * w0.x; acc[1] += a * w0.y; acc[2] += a * w0.z; acc[3] += a * w0.w;
        acc[4] += a * w1.x; acc[5] += a * w1.y; acc[6] += a * w1.z; acc[7] += a * w1.w;
    }
    float* o = h + (size_t)n * DD + ch * 8;
    float4 o0, o1;
    o0.x = acc[0]; o0.y = acc[1]; o0.z = acc[2]; o0.w = acc[3];
    o1.x = acc[4]; o1.y = acc[5]; o1.z = acc[6]; o1.w = acc[7];
    *(float4*)o = o0;
    *(float4*)(o + 4) = o1;
    bf16x8 hb8;
#pragma unroll
    for (int q = 0; q < 8; ++q) hb8[q] = (short)f2b(acc[q]);
    *(bf16x8*)(hb + (size_t)n * DD + ch * 8) = hb8;
}

// ---------------- CSR build (sorted-by-dst edge order) ----------------
__global__ void cnt_edges_k(const int* __restrict__ src, const int* __restrict__ dst,
                            int* __restrict__ icnt, int* __restrict__ ocnt) {
    int e = blockIdx.x * 256 + threadIdx.x;
    if (e < NE) {
        atomicAdd(&icnt[dst[e]], 1);
        atomicAdd(&ocnt[src[e]], 1);
    }
}

__global__ __launch_bounds__(1024) void csr_scan_k(const int* __restrict__ cnt,
                                                   int* __restrict__ off,
                                                   int* __restrict__ cur) {
    __shared__ int part[1024];
    int t = threadIdx.x;
    int base = t * 20;
    int s = 0;
    for (int i = 0; i < 20; ++i) { int idx = base + i; if (idx < NN) s += cnt[idx]; }
    part[t] = s;
    __syncthreads();
    for (int ofs = 1; ofs < 1024; ofs <<= 1) {
        int v = (t >= ofs) ? part[t - ofs] : 0;
        __syncthreads();
        part[t] += v;
        __syncthreads();
    }
    int run = (t == 0) ? 0 : part[t - 1];
    for (int i = 0; i < 20; ++i) {
        int idx = base + i;
        if (idx < NN) { off[idx] = run; cur[idx] = run; run += cnt[idx]; }
    }
    if (t == 1023) off[NN] = run;
}

__global__ void fill_edges_k(const int* __restrict__ src, const int* __restrict__ dst,
                             const float* __restrict__ bond,
                             int* __restrict__ cur, int* __restrict__ ssrc,
                             int* __restrict__ sdst, float* __restrict__ bond_s) {
    int e = blockIdx.x * 256 + threadIdx.x;
    if (e < NE) {
        int d = dst[e];
        int p = atomicAdd(&cur[d], 1);
        ssrc[p] = src[e];
        sdst[p] = d;
        bond_s[p] = bond[e];
    }
}

// ---------------- fused one-time stats: rbf col-sums (blocks <512) + zsum (blocks >=512) ----------------
__global__ __launch_bounds__(256) void rbfzsum_k(const float* __restrict__ bond,
                                                 const unsigned short* __restrict__ hb,
                                                 const int* __restrict__ ocnt,
                                                 const int* __restrict__ icnt,
                                                 float* __restrict__ zr,
                                                 float* __restrict__ zS,
                                                 float* __restrict__ zD) {
    if (blockIdx.x < 512) {
        __shared__ float part[4][32];
        int lane = threadIdx.x & 63;
        int w = threadIdx.x >> 6;
        int col = lane & 31;
        int half = lane >> 5;
        int slot = (blockIdx.x * 4 + w) * 2 + half;
        int nslots = 512 * 8;
        float cen = (float)col * CEN;
        float a = 0.f;
        for (int e = slot; e < NE; e += nslots) {
            float u = bond[e] - cen;
            a += b2f(f2b(__builtin_amdgcn_exp2f(u * u * RBF2)));
        }
        a += __shfl_xor(a, 32, 64);
        if (half == 0) part[w][col] = a;
        __syncthreads();
        if (threadIdx.x < 32) {
            float s = part[0][threadIdx.x] + part[1][threadIdx.x] +
                      part[2][threadIdx.x] + part[3][threadIdx.x];
            unsafeAtomicAdd(&zr[threadIdx.x], s);
        }
    } else {
        int bb = blockIdx.x - 512;  // 0..127
        int t = bb * 256 + threadIdx.x;
        int col = t & 63;
        int n0 = t >> 6;
        int nstride = (128 * 256) >> 6;
        float aS = 0.f, aD = 0.f;
        for (int n = n0; n < NN; n += nstride) {
            float v = b2f(hb[(size_t)n * DD + col]);
            aS += (float)ocnt[n] * v;
            aD += (float)icnt[n] * v;
        }
        unsafeAtomicAdd(&zS[col], aS);
        unsafeAtomicAdd(&zD[col], aD);
    }
}

// ---------------- gather-GEMM, BOTH gates, 512 thr, 40KB LDS, coalesced stores via LDS repack ----------------
__global__ __launch_bounds__(512, 8) void edge_pre3_k(const unsigned short* __restrict__ hb,
                                                      const float* __restrict__ bond_s,
                                                      const unsigned short* __restrict__ Wf, // layer base [2][10240]
                                                      const int* __restrict__ ssrc,
                                                      const int* __restrict__ sdst,
                                                      unsigned short* __restrict__ preIb,
                                                      unsigned short* __restrict__ preUb,
                                                      float* __restrict__ pq) {
    __shared__ bf16x8 WfS[2560];      // 40960 B : both gates; gate-I region reused as repack slots + qred
    unsigned short* tbuf = (unsigned short*)WfS;  // repack slots: wave w at ushort offset w*1152 (16 rows x 72)
    float* qred = (float*)WfS;
    const int bidx = blockIdx.x;      // 0..NBLK-1
    const int lane = threadIdx.x & 63;
    const int w = threadIdx.x >> 6;   // 0..7
    const int r = lane & 15;          // edge-within-tile
    const int c = lane >> 4;          // k-chunk
    const int tile = bidx * 8 + w;    // exactly NT tiles
    const int e = tile * 16 + r;

    int es = ssrc[e];
    int ed = sdst[e];
    float bd = bond_s[e];
    bf16x8 a0 = *(const bf16x8*)(hb + (size_t)es * DD + c * 8);
    bf16x8 a1 = *(const bf16x8*)(hb + (size_t)es * DD + 32 + c * 8);
    bf16x8 a2 = *(const bf16x8*)(hb + (size_t)ed * DD + c * 8);
    bf16x8 a3 = *(const bf16x8*)(hb + (size_t)ed * DD + 32 + c * 8);
    bf16x8 a4;
#pragma unroll
    for (int i = 0; i < 8; ++i) {
        float u = bd - (float)(8 * c + i) * CEN;
        a4[i] = (short)f2b(__builtin_amdgcn_exp2f(u * u * RBF2));
    }

    {
        const bf16x8* Wf8 = (const bf16x8*)Wf;
        for (int i = threadIdx.x; i < 2560; i += 512) WfS[i] = Wf8[i];
    }
    __syncthreads();

    float qI[16], qU[16];
    // gate I
    f32x4 accI[4];
    {
#pragma unroll
        for (int nf = 0; nf < 4; ++nf) { f32x4 z4 = {0.f, 0.f, 0.f, 0.f}; accI[nf] = z4; }
#pragma unroll
        for (int kt = 0; kt < 5; ++kt) {
            bf16x8 a = (kt == 0) ? a0 : (kt == 1) ? a1 : (kt == 2) ? a2 : (kt == 3) ? a3 : a4;
#pragma unroll
            for (int nf = 0; nf < 4; ++nf)
                accI[nf] = __builtin_amdgcn_mfma_f32_16x16x32_bf16(WfS[(kt * 4 + nf) * 64 + lane], a, accI[nf], 0, 0, 0);
        }
#pragma unroll
        for (int nf = 0; nf < 4; ++nf)
#pragma unroll
            for (int j = 0; j < 4; ++j) qI[nf * 4 + j] = accI[nf][j] * accI[nf][j];
    }
    __syncthreads();   // all waves done with gate-I weights -> slots usable

    unsigned short* slot = tbuf + w * 1152;   // 16 rows x 72 ushorts (144 B, 16B-aligned)
    // repack + coalesced store, gate I
    {
#pragma unroll
        for (int nf = 0; nf < 4; ++nf) {
            ushort4 o;
            o.x = f2b(accI[nf][0]); o.y = f2b(accI[nf][1]);
            o.z = f2b(accI[nf][2]); o.w = f2b(accI[nf][3]);
            *(ushort4*)(slot + r * 72 + c * 4 + nf * 16) = o;
        }
        bf16x8 v0 = *(const bf16x8*)(slot + (lane >> 2) * 72 + (lane & 3) * 16);
        bf16x8 v1 = *(const bf16x8*)(slot + (lane >> 2) * 72 + (lane & 3) * 16 + 8);
        unsigned short* dst0 = preIb + (size_t)tile * 1024 + lane * 16;
        *(bf16x8*)dst0 = v0;
        *(bf16x8*)(dst0 + 8) = v1;
    }
    // gate U (reuses a0..a4 in registers; gate-U weights untouched at WfS[1280..])
    {
        f32x4 acc[4];
#pragma unroll
        for (int nf = 0; nf < 4; ++nf) { f32x4 z4 = {0.f, 0.f, 0.f, 0.f}; acc[nf] = z4; }
#pragma unroll
        for (int kt = 0; kt < 5; ++kt) {
            bf16x8 a = (kt == 0) ? a0 : (kt == 1) ? a1 : (kt == 2) ? a2 : (kt == 3) ? a3 : a4;
#pragma unroll
            for (int nf = 0; nf < 4; ++nf)
                acc[nf] = __builtin_amdgcn_mfma_f32_16x16x32_bf16(WfS[1280 + (kt * 4 + nf) * 64 + lane], a, acc[nf], 0, 0, 0);
        }
#pragma unroll
        for (int nf = 0; nf < 4; ++nf) {
            ushort4 o;
            o.x = f2b(acc[nf][0]); o.y = f2b(acc[nf][1]);
            o.z = f2b(acc[nf][2]); o.w = f2b(acc[nf][3]);
            *(ushort4*)(slot + r * 72 + c * 4 + nf * 16) = o;
#pragma unroll
            for (int j = 0; j < 4; ++j) qU[nf * 4 + j] = acc[nf][j] * acc[nf][j];
        }
        bf16x8 v0 = *(const bf16x8*)(slot + (lane >> 2) * 72 + (lane & 3) * 16);
        bf16x8 v1 = *(const bf16x8*)(slot + (lane >> 2) * 72 + (lane & 3) * 16 + 8);
        unsigned short* dst0 = preUb + (size_t)tile * 1024 + lane * 16;
        *(bf16x8*)dst0 = v0;
        *(bf16x8*)(dst0 + 8) = v1;
    }

    // sumsq reduce across the 16 r-lanes (halving tree); then cross-wave via aliased LDS
    float vI = tree16(qI, r);
    float vU = tree16(qU, r);
    int col = (r >> 2) * 16 + c * 4 + (r & 3);
    __syncthreads();   // all waves done with their slots -> qred region safe
    qred[w * 128 + col] = vI;
    qred[w * 128 + 64 + col] = vU;
    __syncthreads();
    if (threadIdx.x < 128) {
        float s8 = 0.f;
#pragma unroll
        for (int ww = 0; ww < 8; ++ww) s8 += qred[ww * 128 + threadIdx.x];
        pq[(size_t)threadIdx.x * NBLK + bidx] = s8;  // rows: 0..63 = qI, 64..127 = qU
    }
}

// ---------------- fused reduce: pq(len NBLK) -> stats[0..127], zpart(len NHB) -> stats[256..383] ----------------
__global__ __launch_bounds__(256) void red2_k(const float* __restrict__ pq,
                                              const float* __restrict__ zpart,
                                              float* __restrict__ stats, int withz) {
    __shared__ float red[256];
    int b = blockIdx.x;
    const float* row;
    float* out;
    int len;
    if (b < 128) { row = pq + (size_t)b * NBLK; out = &stats[b]; len = NBLK; }
    else {
        if (!withz) return;
        row = zpart + (size_t)(b - 128) * NHB; out = &stats[256 + (b - 128)]; len = NHB;
    }
    float s = 0.f;
    for (int i = threadIdx.x; i < len; i += 256) s += row[i];
    red[threadIdx.x] = s;
    __syncthreads();
    for (int ofs = 128; ofs >= 1; ofs >>= 1) {
        if (threadIdx.x < ofs) red[threadIdx.x] += red[threadIdx.x + ofs];
        __syncthreads();
    }
    if (threadIdx.x == 0) *out = red[0];
}

// ---------------- BN coeffs gate/update (256 thr: 4-way k-split + LDS reduce) ----------------
// coeff emitted with log2e folded: [0]=-L2E*sI, [64]=-L2E*tI, [128]=L2E*sU, [192]=L2E*tU
__global__ __launch_bounds__(256) void fin_iu_k(const float* __restrict__ stats,
                                                const unsigned short* __restrict__ Wf,
                                                const float* __restrict__ gi, const float* __restrict__ bbi,
                                                const float* __restrict__ gu, const float* __restrict__ bbu,
                                                float* __restrict__ coeff) {
    __shared__ float redI[256], redU[256];
    int t = threadIdx.x;
    int j = t & 63, part = t >> 6;  // 4 parts
    int nf = j >> 4, rr = j & 15;
    float muI = 0.f, muU = 0.f;
    for (int k = part; k < 160; k += 4) {
        float zs = (k < 128) ? stats[256 + k] : stats[384 + k - 128];
        int kt = k >> 5, rem = k & 31, cc = rem >> 3, ii = rem & 7;
        int f = kt * 2048 + nf * 512 + (cc * 16 + rr) * 8 + ii;
        muI += zs * b2f(Wf[f]);
        muU += zs * b2f(Wf[10240 + f]);
    }
    redI[t] = muI;
    redU[t] = muU;
    __syncthreads();
    if (t < 64) {
        muI = redI[t] + redI[64 + t] + redI[128 + t] + redI[192 + t];
        muU = redU[t] + redU[64 + t] + redU[128 + t] + redU[192 + t];
        const float invE = 1.f / (float)NE;
        muI *= invE; muU *= invE;
        float varI = stats[t] * invE - muI * muI;
        float sI = gi[t] * rsqrtf(varI + 1e-5f);
        float tI = bbi[t] - muI * sI;
        float varU = stats[64 + t] * invE - muU * muU;
        float sU = gu[t] * rsqrtf(varU + 1e-5f);
        float tU = bbu[t] - muU * sU;
        coeff[t]       = -L2E * sI;
        coeff[64 + t]  = -L2E * tI;
        coeff[128 + t] =  L2E * sU;
        coeff[192 + t] =  L2E * tU;
    }
}

// ---------------- node-parallel apply (32 thr/node, x8 loads) + fused m stats ----------------
// act = log(1+2^xu') * rcp(1+2^xi')  — global ln2 factor dropped (BN scale-invariant)
__global__ __launch_bounds__(256) void apply_node_k(const unsigned short* __restrict__ preIb,
                                                    const unsigned short* __restrict__ preUb,
                                                    const int* __restrict__ eoff,
                                                    const float* __restrict__ coeff,
                                                    float* __restrict__ m,
                                                    float* __restrict__ mpart) {
    __shared__ float ps[64][8];
    __shared__ float pq2[64][8];
    int ch = threadIdx.x & 7;
    int qtr = (threadIdx.x >> 3) & 3;
    int nl = threadIdx.x >> 5;              // 0..7
    int n = blockIdx.x * 8 + nl;
    float sIv[8], tIv[8], sUv[8], tUv[8];
#pragma unroll
    for (int q = 0; q < 8; ++q) {
        int col = ch * 8 + q;
        sIv[q] = coeff[col];       tIv[q] = coeff[64 + col];
        sUv[q] = coeff[128 + col]; tUv[q] = coeff[192 + col];
    }
    int b = eoff[n], e = eoff[n + 1];
    float acc[8];
#pragma unroll
    for (int q = 0; q < 8; ++q) acc[q] = 0.f;
    for (int p = b + qtr; p < e; p += 4) {
        bf16x8 vi = *(const bf16x8*)(preIb + (size_t)p * DD + ch * 8);
        bf16x8 vu = *(const bf16x8*)(preUb + (size_t)p * DD + ch * 8);
#pragma unroll
        for (int q = 0; q < 8; ++q) {
            float xi = fmaf(b2f((unsigned short)vi[q]), sIv[q], tIv[q]);
            float den = 1.f + __builtin_amdgcn_exp2f(xi);
            float xu = fmaf(b2f((unsigned short)vu[q]), sUv[q], tUv[q]);
            float lu = __builtin_amdgcn_logf(1.f + __builtin_amdgcn_exp2f(xu));
            acc[q] = fmaf(lu, __builtin_amdgcn_rcpf(den), acc[q]);
        }
    }
    // merge the four quarter-threads (lanes differ by 8 and 16 within the 32-lane node group)
#pragma unroll
    for (int q = 0; q < 8; ++q) {
        acc[q] += __shfl_xor(acc[q], 8, 64);
        acc[q] += __shfl_xor(acc[q], 16, 64);
    }
    if (qtr == 0) {
        float* mp = m + (size_t)n * DD + ch * 8;
        float4 v0, v1;
        v0.x = acc[0]; v0.y = acc[1]; v0.z = acc[2]; v0.w = acc[3];
        v1.x = acc[4]; v1.y = acc[5]; v1.z = acc[6]; v1.w = acc[7];
        *(float4*)mp = v0;
        *(float4*)(mp + 4) = v1;
        int idx = nl * 8 + ch;  // 0..63
#pragma unroll
        for (int q = 0; q < 8; ++q) {
            ps[idx][q] = acc[q];
            pq2[idx][q] = acc[q] * acc[q];
        }
    }
    __syncthreads();
    if (threadIdx.x < 64) {
        int j = threadIdx.x;
        int chh = j >> 3, qq = j & 7;
        float s = 0.f, q2 = 0.f;
#pragma unroll
        for (int nn = 0; nn < 8; ++nn) {
            s += ps[nn * 8 + chh][qq];
            q2 += pq2[nn * 8 + chh][qq];
        }
        mpart[(size_t)j * NAB + blockIdx.x] = s;
        mpart[(size_t)(64 + j) * NAB + blockIdx.x] = q2;
    }
}

// ---------------- fused mpart reduce + BN(m) coeffs: 64 blocks, block j -> col j ----------------
__global__ __launch_bounds__(256) void fin_n3_k(const float* __restrict__ mpart,
                                                const float* __restrict__ gn,
                                                const float* __restrict__ bbn,
                                                float* __restrict__ coeffN) {
    __shared__ float red1[256], red2[256];
    int j = blockIdx.x; // 0..63
    float s1 = 0.f, s2 = 0.f;
    for (int i = threadIdx.x; i < NAB; i += 256) {
        s1 += mpart[(size_t)j * NAB + i];
        s2 += mpart[(size_t)(64 + j) * NAB + i];
    }
    red1[threadIdx.x] = s1;
    red2[threadIdx.x] = s2;
    __syncthreads();
    for (int ofs = 128; ofs >= 1; ofs >>= 1) {
        if (threadIdx.x < ofs) {
            red1[threadIdx.x] += red1[threadIdx.x + ofs];
            red2[threadIdx.x] += red2[threadIdx.x + ofs];
        }
        __syncthreads();
    }
    if (threadIdx.x == 0) {
        const float invN = 1.f / (float)NN;
        float mu = red1[0] * invN;
        float var = red2[0] * invN - mu * mu;
        float sc = gn[j] * rsqrtf(var + 1e-5f);
        coeffN[j] = sc;
        coeffN[64 + j] = bbn[j] - mu * sc;
    }
}

// ---------------- h = sp(h + bn(m)), 8-wide; non-fin fuses next-layer zsum partials ----------------
__global__ __launch_bounds__(256) void h_update_k(float* __restrict__ h,
                                                  unsigned short* __restrict__ hb,
                                                  const float* __restrict__ m,
                                                  const float* __restrict__ coeffN,
                                                  const int* __restrict__ ocnt,
                                                  const int* __restrict__ icnt,
                                                  float* __restrict__ zpart,
                                                  int fin) {
    __shared__ float wzs[4][8][8], wzd[4][8][8];
    int t = blockIdx.x * 256 + threadIdx.x;  // NN*DD/8 = 160000 threads exactly
    int n = t >> 3, ch = t & 7;
    int base = n * DD + ch * 8;
    float4 m0 = *(const float4*)(m + base);
    float4 m1 = *(const float4*)(m + base + 4);
    float4 h0 = *(const float4*)(h + base);
    float4 h1 = *(const float4*)(h + base + 4);
    float mv[8] = {m0.x, m0.y, m0.z, m0.w, m1.x, m1.y, m1.z, m1.w};
    float hv[8] = {h0.x, h0.y, h0.z, h0.w, h1.x, h1.y, h1.z, h1.w};
    unsigned short hbv[8];
#pragma unroll
    for (int q = 0; q < 8; ++q) {
        int col = ch * 8 + q;
        float v = sp_(hv[q] + mv[q] * coeffN[col] + coeffN[64 + col]);
        hv[q] = v;
        hbv[q] = f2b(v);
    }
    float4 o0, o1;
    o0.x = hv[0]; o0.y = hv[1]; o0.z = hv[2]; o0.w = hv[3];
    o1.x = hv[4]; o1.y = hv[5]; o1.z = hv[6]; o1.w = hv[7];
    *(float4*)(h + base) = o0;
    *(float4*)(h + base + 4) = o1;
    if (fin) return;  // pooling handled by pool_head_k from h

    bf16x8 hb8;
#pragma unroll
    for (int q = 0; q < 8; ++q) hb8[q] = (short)hbv[q];
    *(bf16x8*)(hb + base) = hb8;

    float oc = (float)ocnt[n], ic = (float)icnt[n];
    float zs8[8], zd8[8];
#pragma unroll
    for (int q = 0; q < 8; ++q) {
        float r = b2f(hbv[q]);
        zs8[q] = r * oc;
        zd8[q] = r * ic;
    }
#pragma unroll
    for (int mk = 8; mk <= 32; mk <<= 1) {
#pragma unroll
        for (int q = 0; q < 8; ++q) {
            zs8[q] += __shfl_xor(zs8[q], mk, 64);
            zd8[q] += __shfl_xor(zd8[q], mk, 64);
        }
    }
    int lane = threadIdx.x & 63;
    int w = threadIdx.x >> 6;
    if (lane < 8) {
#pragma unroll
        for (int q = 0; q < 8; ++q) {
            wzs[w][lane][q] = zs8[q];
            wzd[w][lane][q] = zd8[q];
        }
    }
    __syncthreads();
    if (threadIdx.x < 64) {
        int chh = threadIdx.x >> 3, qq = threadIdx.x & 7; // col = chh*8+qq = threadIdx.x
        float s = wzs[0][chh][qq] + wzs[1][chh][qq] + wzs[2][chh][qq] + wzs[3][chh][qq];
        float d = wzd[0][chh][qq] + wzd[1][chh][qq] + wzd[2][chh][qq] + wzd[3][chh][qq];
        zpart[(size_t)threadIdx.x * NHB + blockIdx.x] = s;
        zpart[(size_t)(64 + threadIdx.x) * NHB + blockIdx.x] = d;
    }
}

// ---------------- fused segmented pooling + head: one block per graph ----------------
__global__ __launch_bounds__(256) void pool_head_k(const float* __restrict__ h,
                                                   const int* __restrict__ gid,
                                                   const float* __restrict__ fcW,
                                                   const float* __restrict__ fcb,
                                                   const float* __restrict__ oW,
                                                   const float* __restrict__ ob,
                                                   float* __restrict__ out) {
    __shared__ int s_lo, s_hi;
    __shared__ float red4[4][DD];
    __shared__ float feats[DD];
    __shared__ float red[FF];
    int g = blockIdx.x;
    if (threadIdx.x == 0) {
        int lo = 0, hi = NN;
        while (lo < hi) { int mid = (lo + hi) >> 1; if (gid[mid] < g) lo = mid + 1; else hi = mid; }
        s_lo = lo;
        int lo2 = lo, hi2 = NN;
        while (lo2 < hi2) { int mid = (lo2 + hi2) >> 1; if (gid[mid] < g + 1) lo2 = mid + 1; else hi2 = mid; }
        s_hi = lo2;
    }
    __syncthreads();
    int lo = s_lo, hi = s_hi;
    int col = threadIdx.x & 63;
    int rr = threadIdx.x >> 6;
    float s = 0.f;
    for (int n = lo + rr; n < hi; n += 4) s += h[(size_t)n * DD + col];
    red4[rr][col] = s;
    __syncthreads();
    if (threadIdx.x < 64) {
        float v = red4[0][col] + red4[1][col] + red4[2][col] + red4[3][col];
        float c = fmaxf((float)(hi - lo), 1.f);
        feats[threadIdx.x] = sp_(v / c);
    }
    __syncthreads();
    if (threadIdx.x < FF) {
        int t = threadIdx.x;
        float a = fcb[t];
#pragma unroll 1
        for (int j = 0; j < DD; ++j) a += feats[j] * fcW[j * FF + t];
        float y = sp_(sp_(a));
        red[t] = y * oW[t];
    }
    __syncthreads();
    for (int s2 = 64; s2 >= 1; s2 >>= 1) {
        if (threadIdx.x < s2) red[threadIdx.x] += red[threadIdx.x + s2];
        __syncthreads();
    }
    if (threadIdx.x == 0) out[g] = red[0] + ob[0];
}

extern "C" void kernel_launch(void* const* d_in, const int* in_sizes, int n_in,
                              void* d_out, int out_size, void* d_ws, size_t ws_size,
                              hipStream_t stream) {
    const float* af   = (const float*)d_in[0];
    const float* bond = (const float*)d_in[1];
    const int*   src  = (const int*)d_in[2];
    const int*   dst  = (const int*)d_in[3];
    const int*   gid  = (const int*)d_in[4];
    const float* embW = (const float*)d_in[5];
    const float* embB = (const float*)d_in[6];
    const float* Wi   = (const float*)d_in[7];
    const float* gi   = (const float*)d_in[9];
    const float* bbi  = (const float*)d_in[10];
    const float* Wu   = (const float*)d_in[11];
    const float* gu   = (const float*)d_in[13];
    const float* bbu  = (const float*)d_in[14];
    const float* gn   = (const float*)d_in[15];
    const float* bbn  = (const float*)d_in[16];
    const float* fcW  = (const float*)d_in[17];
    const float* fcb  = (const float*)d_in[18];
    const float* oW   = (const float*)d_in[19];
    const float* ob   = (const float*)d_in[20];
    float* out = (float*)d_out;

    char* ws = (char*)d_ws;
    size_t off = 0;
    auto take = [&](size_t bytes) {
        size_t o = off;
        off += (bytes + 255) & ~(size_t)255;
        return o;
    };
    float* h     = (float*)(ws + take((size_t)NN * DD * 4));
    float* m     = (float*)(ws + take((size_t)NN * DD * 4));
    float* stats = (float*)(ws + take(512 * 4));
    float* coeff = (float*)(ws + take(512 * 4)); // [sI2,tI2,sU2,tU2 | sN,tN]
    float* pq    = (float*)(ws + take((size_t)128 * NBLK * 4)); // 1.28 MB partial sumsq
    float* mpart = (float*)(ws + take((size_t)128 * NAB * 4));  // 1.28 MB m-stat partials
    float* zpart = (float*)(ws + take((size_t)128 * NHB * 4));  // 320 KB zsum partials
    int* ecount  = (int*)(ws + take((size_t)NN * 4));        // indeg
    int* ocount  = (int*)(ws + take((size_t)NN * 4));        // outdeg (contiguous after ecount)
    int* eoff    = (int*)(ws + take((size_t)(NN + 1) * 4));
    int* ecur    = (int*)(ws + take((size_t)NN * 4));
    int* ssrc    = (int*)(ws + take((size_t)NE * 4));
    int* sdst    = (int*)(ws + take((size_t)NE * 4));
    float* bond_s = (float*)(ws + take((size_t)NE * 4));
    unsigned short* hb    = (unsigned short*)(ws + take((size_t)NN * DD * 2));
    unsigned short* preIb = (unsigned short*)(ws + take((size_t)NE * DD * 2));
    unsigned short* preUb = (unsigned short*)(ws + take((size_t)NE * DD * 2));
    unsigned short* Wf    = (unsigned short*)(ws + take((size_t)6 * 10240 * 2));

    // zero: ecount+ocount (contiguous), stats
    hipMemsetAsync((void*)ecount, 0, 2 * (((size_t)NN * 4 + 255) & ~(size_t)255), stream);
    hipMemsetAsync((void*)stats, 0, 512 * 4, stream);

    embed_k<<<NN / 32 + 6, 256, 0, stream>>>(af, embW, embB, h, hb, Wi, Wu, Wf);

    cnt_edges_k<<<(NE + 255) / 256, 256, 0, stream>>>(src, dst, ecount, ocount);
    csr_scan_k<<<1, 1024, 0, stream>>>(ecount, eoff, ecur);
    fill_edges_k<<<(NE + 255) / 256, 256, 0, stream>>>(src, dst, bond, ecur, ssrc, sdst, bond_s);
    rbfzsum_k<<<640, 256, 0, stream>>>(bond, hb, ocount, ecount, stats + 384, stats + 256,
                                       stats + 320);

    for (int l = 0; l < 3; ++l) {
        const unsigned short* Wfl = Wf + (size_t)l * 2 * 10240;
        edge_pre3_k<<<NBLK, 512, 0, stream>>>(hb, bond_s, Wfl, ssrc, sdst, preIb, preUb, pq);
        red2_k<<<256, 256, 0, stream>>>(pq, zpart, stats, l > 0 ? 1 : 0);
        fin_iu_k<<<1, 256, 0, stream>>>(stats, Wfl, gi + l * DD, bbi + l * DD,
                                        gu + l * DD, bbu + l * DD, coeff);
        apply_node_k<<<NAB, 256, 0, stream>>>(preIb, preUb, eoff, coeff, m, mpart);
        fin_n3_k<<<64, 256, 0, stream>>>(mpart, gn + l * DD, bbn + l * DD, coeff + 256);
        h_update_k<<<NHB, 256, 0, stream>>>(h, hb, m, coeff + 256, ocount, ecount,
                                            zpart, l == 2 ? 1 : 0);
    }

    pool_head_k<<<NG, 256, 0, stream>>>(h, gid, fcW, fcb, oW, ob, out);
}